// Round 2
// baseline (599.918 us; speedup 1.0000x reference)
//
#include <hip/hip_runtime.h>
#include <hip/hip_bf16.h>
#include <math.h>

#define B_  32
#define N_  100
#define G_  32
#define D_  1024
#define DG_ 32
#define FD_ 64

// ---------------------------------------------------------------------------
// Mask dtype detection: if any 32-bit word of the mask buffer exceeds 1, the
// buffer must be packed bytes (bool); int32 0/1 words never exceed 1.
// Scans only the first BNGN/4 words = safe under both layouts.
// ---------------------------------------------------------------------------
__global__ __launch_bounds__(256) void detect_mask_kernel(
    const unsigned int* __restrict__ m, int nwords, int* __restrict__ flag)
{
    int v = 0;
    for (int i = blockIdx.x * 256 + threadIdx.x; i < nwords; i += gridDim.x * 256)
        v |= (m[i] > 1u) ? 1 : 0;
    if (__any(v) && (threadIdx.x & 63) == 0)
        atomicOr(flag, 1);
}

// ---------------------------------------------------------------------------
// SGEMM NT: C[m][n] = sum_c A[m][c] * W[n][c] + bias[n]
// A: (3200,1024), W: (1024,1024), both row-major over c (K-contiguous).
// 64x64 tile, BK=16, 256 threads, 4x4 microtile.
// ---------------------------------------------------------------------------
__global__ __launch_bounds__(256) void sgemm_nt(
    const float* __restrict__ A, const float* __restrict__ W,
    const float* __restrict__ bias, float* __restrict__ C)
{
    __shared__ float As[16][68];  // [k][m]
    __shared__ float Ws[16][68];  // [k][n]

    const int m0 = blockIdx.x * 64;
    const int n0 = blockIdx.y * 64;
    const int t  = threadIdx.x;
    const int tx = t & 15, ty = t >> 4;
    const int lr = t >> 2;          // 0..63 row within tile
    const int lc = (t & 3) * 4;     // 0,4,8,12 col within BK

    float acc[4][4] = {};

    for (int k0 = 0; k0 < D_; k0 += 16) {
        float4 a4 = *reinterpret_cast<const float4*>(&A[(m0 + lr) * D_ + k0 + lc]);
        float4 w4 = *reinterpret_cast<const float4*>(&W[(n0 + lr) * D_ + k0 + lc]);
        __syncthreads();   // previous tile's compute done before overwrite
        As[lc + 0][lr] = a4.x; As[lc + 1][lr] = a4.y;
        As[lc + 2][lr] = a4.z; As[lc + 3][lr] = a4.w;
        Ws[lc + 0][lr] = w4.x; Ws[lc + 1][lr] = w4.y;
        Ws[lc + 2][lr] = w4.z; Ws[lc + 3][lr] = w4.w;
        __syncthreads();
#pragma unroll
        for (int kk = 0; kk < 16; ++kk) {
            float av[4], bv[4];
#pragma unroll
            for (int i = 0; i < 4; ++i) av[i] = As[kk][ty * 4 + i];
#pragma unroll
            for (int j = 0; j < 4; ++j) bv[j] = Ws[kk][tx * 4 + j];
#pragma unroll
            for (int i = 0; i < 4; ++i)
#pragma unroll
                for (int j = 0; j < 4; ++j) acc[i][j] += av[i] * bv[j];
        }
    }

#pragma unroll
    for (int i = 0; i < 4; ++i) {
        const int m = m0 + ty * 4 + i;
#pragma unroll
        for (int j = 0; j < 4; ++j) {
            const int n = n0 + tx * 4 + j;
            const float bv = bias ? bias[n] : 0.0f;
            C[m * D_ + n] = acc[i][j] + bv;
        }
    }
}

// ---------------------------------------------------------------------------
// Position embedding + fc1 + relu + log  ->  logw[b,q,g,k]
// One block per (b,q).
// ---------------------------------------------------------------------------
__global__ __launch_bounds__(256) void pos_fc1_kernel(
    const float* __restrict__ bbox, const float* __restrict__ fc1_w,
    const float* __restrict__ fc1_b, float* __restrict__ logw)
{
    __shared__ float emb[N_][FD_ + 1];   // 100 x 65
    __shared__ float w1[G_][FD_];
    __shared__ float b1[G_];
    __shared__ float dimt[8];

    const int b = blockIdx.x / N_;
    const int q = blockIdx.x % N_;
    const int t = threadIdx.x;

    for (int i = t; i < G_ * FD_; i += 256) w1[i >> 6][i & 63] = fc1_w[i];
    if (t < G_) b1[t] = fc1_b[t];
    if (t < 8)  dimt[t] = powf(1000.0f, (float)t * 0.125f);

    const float* bq = &bbox[(b * N_ + q) * 4];
    const float qx0 = bq[0], qy0 = bq[1], qx1 = bq[2], qy1 = bq[3];
    const float bwq = qx1 - qx0 + 1.0f, bhq = qy1 - qy0 + 1.0f;
    const float cxq = 0.5f * (qx0 + qx1), cyq = 0.5f * (qy0 + qy1);

    __syncthreads();

    // Phase A: emb[k][f]
    for (int idx = t; idx < N_ * 32; idx += 256) {
        const int k = idx >> 5;
        const int p = (idx >> 3) & 3;
        const int j = idx & 7;
        const float* bk = &bbox[(b * N_ + k) * 4];
        const float kx0 = bk[0], ky0 = bk[1], kx1 = bk[2], ky1 = bk[3];
        const float bwk = kx1 - kx0 + 1.0f, bhk = ky1 - ky0 + 1.0f;
        const float cxk = 0.5f * (kx0 + kx1), cyk = 0.5f * (ky0 + ky1);
        float pos;
        if      (p == 0) pos = logf(fmaxf(fabsf((cxq - cxk) / bwq), 1e-3f));
        else if (p == 1) pos = logf(fmaxf(fabsf((cyq - cyk) / bhq), 1e-3f));
        else if (p == 2) pos = logf(bwq / bwk);
        else             pos = logf(bhq / bhk);
        const float dv = 100.0f * pos / dimt[j];
        emb[k][p * 16 + j]     = sinf(dv);
        emb[k][p * 16 + 8 + j] = cosf(dv);
    }
    __syncthreads();

    // Phase B: logw[b,q,g,k] = log(max(relu(emb[k]·w1[g] + b1[g]), 1e-6))
    for (int idx = t; idx < G_ * N_; idx += 256) {
        const int g = idx / N_;
        const int k = idx % N_;
        float acc = b1[g];
#pragma unroll
        for (int f = 0; f < FD_; ++f) acc += emb[k][f] * w1[g][f];
        const float aw = fmaxf(acc, 0.0f);
        logw[((b * N_ + q) * G_ + g) * N_ + k] = logf(fmaxf(aw, 1e-6f));
    }
}

// ---------------------------------------------------------------------------
// Attention: one block per (b,g). f32 output.
// ---------------------------------------------------------------------------
__global__ __launch_bounds__(256) void attn_kernel(
    const float* __restrict__ qbuf, const float* __restrict__ kbuf,
    const float* __restrict__ fkbuf, const float* __restrict__ logw,
    const unsigned char* __restrict__ mask8, const int* __restrict__ mask32,
    const int* __restrict__ flag, const float* __restrict__ feat,
    const float* __restrict__ conv_b, float* __restrict__ out)
{
    __shared__ float qs[N_][DG_ + 1];
    __shared__ float ks[N_][DG_ + 1];
    __shared__ float fs[N_][DG_ + 1];
    __shared__ float s[50][N_ + 1];

    const int b = blockIdx.x / G_;
    const int g = blockIdx.x % G_;
    const int t = threadIdx.x;
    const bool bytemask = (*flag != 0);
    const float scale = 0.17677669529663687f;  // 1/sqrt(32)

    for (int i = t; i < N_ * 8; i += 256) {
        const int n = i >> 3, c4 = (i & 7) * 4;
        const int gb = (b * N_ + n) * D_ + g * DG_ + c4;
        float4 v = *reinterpret_cast<const float4*>(&qbuf[gb]);
        qs[n][c4] = v.x; qs[n][c4 + 1] = v.y; qs[n][c4 + 2] = v.z; qs[n][c4 + 3] = v.w;
        float4 w = *reinterpret_cast<const float4*>(&kbuf[gb]);
        ks[n][c4] = w.x; ks[n][c4 + 1] = w.y; ks[n][c4 + 2] = w.z; ks[n][c4 + 3] = w.w;
        float4 f = *reinterpret_cast<const float4*>(&fkbuf[gb]);
        fs[n][c4] = f.x; fs[n][c4 + 1] = f.y; fs[n][c4 + 2] = f.z; fs[n][c4 + 3] = f.w;
    }
    __syncthreads();

    for (int h = 0; h < 2; ++h) {
        const int q0 = h * 50;
        // scores
        for (int idx = t; idx < 50 * N_; idx += 256) {
            const int qr = idx / N_, k = idx % N_;
            const int qi = q0 + qr;
            float acc = 0.0f;
#pragma unroll
            for (int d = 0; d < DG_; ++d) acc += qs[qi][d] * ks[k][d];
            const int base = ((b * N_ + qi) * G_ + g) * N_ + k;
            const float v = acc * scale + logw[base];
            const bool msk = bytemask ? (mask8[base] != 0) : (mask32[base] != 0);
            s[qr][k] = msk ? -1e9f : v;
        }
        __syncthreads();
        // row softmax
        if (t < 50) {
            float mx = -1e30f;
            for (int k = 0; k < N_; ++k) mx = fmaxf(mx, s[t][k]);
            float sum = 0.0f;
            for (int k = 0; k < N_; ++k) {
                const float e = expf(s[t][k] - mx);
                s[t][k] = e; sum += e;
            }
            const float inv = 1.0f / sum;
            for (int k = 0; k < N_; ++k) s[t][k] *= inv;
        }
        __syncthreads();
        // PV + bias + residual + relu -> f32
        for (int idx = t; idx < 50 * DG_; idx += 256) {
            const int qr = idx / DG_, o = idx % DG_;
            const int qi = q0 + qr;
            float acc = 0.0f;
#pragma unroll 4
            for (int k = 0; k < N_; ++k) acc += s[qr][k] * fs[k][o];
            const int col = g * DG_ + o;
            const int gi = (b * N_ + qi) * D_ + col;
            const float r = feat[gi] + acc + conv_b[col];
            out[gi] = fmaxf(r, 0.0f);
        }
        __syncthreads();
    }
}

// ---------------------------------------------------------------------------
extern "C" void kernel_launch(void* const* d_in, const int* in_sizes, int n_in,
                              void* d_out, int out_size, void* d_ws, size_t ws_size,
                              hipStream_t stream)
{
    const float* feat   = (const float*)d_in[0];
    const float* bbox   = (const float*)d_in[1];
    const void*  maskp  = d_in[2];
    const float* fc1_w  = (const float*)d_in[3];
    const float* fc1_b  = (const float*)d_in[4];
    const float* q_w    = (const float*)d_in[5];
    const float* q_b    = (const float*)d_in[6];
    const float* k_w    = (const float*)d_in[7];
    const float* k_b    = (const float*)d_in[8];
    const float* conv_w = (const float*)d_in[9];
    const float* conv_b = (const float*)d_in[10];

    float* ws = (float*)d_ws;
    const int BN_D  = B_ * N_ * D_;          // 3,276,800
    const int BNGN  = B_ * N_ * G_ * N_;     // 10,240,000
    float* qbuf  = ws;
    float* kbuf  = ws + BN_D;
    float* fkbuf = ws + 2 * BN_D;
    float* logw  = ws + 3 * BN_D;
    int*   flag  = (int*)(ws + 3 * BN_D + BNGN);

    hipMemsetAsync(flag, 0, sizeof(int), stream);
    detect_mask_kernel<<<256, 256, 0, stream>>>((const unsigned int*)maskp,
                                                BNGN / 4, flag);

    dim3 gg(B_ * N_ / 64, D_ / 64);  // (50,16)
    sgemm_nt<<<gg, 256, 0, stream>>>(feat, q_w, q_b, qbuf);
    sgemm_nt<<<gg, 256, 0, stream>>>(feat, k_w, k_b, kbuf);
    sgemm_nt<<<gg, 256, 0, stream>>>(feat, conv_w, nullptr, fkbuf);

    pos_fc1_kernel<<<B_ * N_, 256, 0, stream>>>(bbox, fc1_w, fc1_b, logw);

    attn_kernel<<<B_ * G_, 256, 0, stream>>>(qbuf, kbuf, fkbuf, logw,
                                             (const unsigned char*)maskp,
                                             (const int*)maskp, flag, feat,
                                             conv_b, (float*)d_out);
}

// Round 3
// 292.172 us; speedup vs baseline: 2.0533x; 2.0533x over previous
//
#include <hip/hip_runtime.h>
#include <math.h>

#define B_  32
#define N_  100
#define G_  32
#define D_  1024
#define DG_ 32
#define FD_ 64

typedef __attribute__((ext_vector_type(8))) short short8;
typedef __attribute__((ext_vector_type(8))) unsigned short ushort8;
typedef __attribute__((ext_vector_type(4))) float f32x4;

__device__ inline unsigned short f2bf(float f) {
    unsigned int x = __float_as_uint(f);
    unsigned int r = (x + 0x7fffu + ((x >> 16) & 1u)) >> 16;  // RNE
    return (unsigned short)r;
}

__device__ inline void load_lds16(const void* g, void* l) {
    __builtin_amdgcn_global_load_lds(
        (const __attribute__((address_space(1))) void*)g,
        (__attribute__((address_space(3))) void*)l, 16, 0, 0);
}

// ---------------------------------------------------------------------------
// Mask dtype detection (bool-byte vs int32).
// ---------------------------------------------------------------------------
__global__ __launch_bounds__(256) void detect_mask_kernel(
    const unsigned int* __restrict__ m, int nwords, int* __restrict__ flag)
{
    int v = 0;
    for (int i = blockIdx.x * 256 + threadIdx.x; i < nwords; i += gridDim.x * 256)
        v |= (m[i] > 1u) ? 1 : 0;
    if (__any(v) && (threadIdx.x & 63) == 0)
        atomicOr(flag, 1);
}

// ---------------------------------------------------------------------------
// f32 -> bf16 cast, 8 elems/thread, n8 = n/8 tasks.
// ---------------------------------------------------------------------------
__global__ __launch_bounds__(256) void cast_f32_bf16(
    const float* __restrict__ src, unsigned short* __restrict__ dst, int n8)
{
    const int i = blockIdx.x * 256 + threadIdx.x;
    if (i >= n8) return;
    const float4 a = reinterpret_cast<const float4*>(src)[i * 2 + 0];
    const float4 b = reinterpret_cast<const float4*>(src)[i * 2 + 1];
    ushort8 o;
    o[0] = f2bf(a.x); o[1] = f2bf(a.y); o[2] = f2bf(a.z); o[3] = f2bf(a.w);
    o[4] = f2bf(b.x); o[5] = f2bf(b.y); o[6] = f2bf(b.z); o[7] = f2bf(b.w);
    *reinterpret_cast<ushort8*>(&dst[i * 8]) = o;
}

// ---------------------------------------------------------------------------
// bf16 MFMA GEMM NT: C[m][n] = sum_k A[m][k]*W[n][k] + bias[n]
// M=3200, N=1024, K=1024. 128x128 tile, BK=64, 4 waves, 4x4 16x16 frags.
// grid.z in {0,1,2} selects (W,bias,C) for q / k / fk.
// LDS staged via global_load_lds(16B) with pre-swizzled source
// (byte ^= (row&7)<<4 within each 128B row); fragment reads apply same XOR.
// ---------------------------------------------------------------------------
__global__ __launch_bounds__(256) void mfma_gemm_nt(
    const unsigned short* __restrict__ A,
    const unsigned short* __restrict__ Wq,
    const unsigned short* __restrict__ Wk,
    const unsigned short* __restrict__ Wc,
    const float* __restrict__ bq, const float* __restrict__ bk,
    float* __restrict__ Cq, float* __restrict__ Ck, float* __restrict__ Cf)
{
    __shared__ short As[128 * 64];
    __shared__ short Bs[128 * 64];

    const int z = blockIdx.z;
    const unsigned short* W = (z == 0) ? Wq : (z == 1) ? Wk : Wc;
    const float* bias        = (z == 0) ? bq : (z == 1) ? bk : nullptr;
    float* C                 = (z == 0) ? Cq : (z == 1) ? Ck : Cf;

    const int m0 = blockIdx.x * 128;
    const int n0 = blockIdx.y * 128;
    const int t = threadIdx.x;
    const int lane = t & 63;
    const int wid = t >> 6;
    const int wr = wid >> 1, wc = wid & 1;

    f32x4 acc[4][4] = {};

    for (int k0 = 0; k0 < D_; k0 += 64) {
#pragma unroll
        for (int c = 0; c < 4; ++c) {
            const int idx16 = c * 256 + t;
            const int row = idx16 >> 3;                               // tile row
            const int colb = ((idx16 & 7) * 16) ^ ((row & 7) << 4);   // swizzled src byte
            const char* ga = (const char*)(A + (size_t)(m0 + row) * D_ + k0) + colb;
            const char* gw = (const char*)(W + (size_t)(n0 + row) * D_ + k0) + colb;
            char* la = (char*)As + (c * 256 + wid * 64) * 16;
            char* lb = (char*)Bs + (c * 256 + wid * 64) * 16;
            load_lds16(ga, la);
            load_lds16(gw, lb);
        }
        __syncthreads();   // drains vmcnt(0): staging visible

#pragma unroll
        for (int ks = 0; ks < 2; ++ks) {
            short8 afr[4], bfr[4];
            const int kb = ks * 64 + (lane >> 4) * 16;  // byte within 128B row
#pragma unroll
            for (int f = 0; f < 4; ++f) {
                const int am = wr * 64 + f * 16 + (lane & 15);
                afr[f] = *reinterpret_cast<const short8*>(
                    (const char*)As + am * 128 + (kb ^ ((am & 7) << 4)));
                const int bn = wc * 64 + f * 16 + (lane & 15);
                bfr[f] = *reinterpret_cast<const short8*>(
                    (const char*)Bs + bn * 128 + (kb ^ ((bn & 7) << 4)));
            }
#pragma unroll
            for (int i = 0; i < 4; ++i)
#pragma unroll
                for (int j = 0; j < 4; ++j)
                    acc[i][j] = __builtin_amdgcn_mfma_f32_16x16x32_bf16(
                        afr[i], bfr[j], acc[i][j], 0, 0, 0);
        }
        __syncthreads();   // protect LDS before next stage
    }

#pragma unroll
    for (int j = 0; j < 4; ++j) {
        const int col = n0 + wc * 64 + j * 16 + (lane & 15);
        const float bv = bias ? bias[col] : 0.0f;
#pragma unroll
        for (int i = 0; i < 4; ++i) {
            const int mbase = m0 + wr * 64 + i * 16 + (lane >> 4) * 4;
#pragma unroll
            for (int r = 0; r < 4; ++r)
                C[(size_t)(mbase + r) * D_ + col] = acc[i][j][r] + bv;
        }
    }
}

// ---------------------------------------------------------------------------
// Position embedding + fc1 + relu + log  ->  logw[b,q,g,k]
// ---------------------------------------------------------------------------
__global__ __launch_bounds__(256) void pos_fc1_kernel(
    const float* __restrict__ bbox, const float* __restrict__ fc1_w,
    const float* __restrict__ fc1_b, float* __restrict__ logw)
{
    __shared__ float emb[N_][FD_ + 1];   // 100 x 65
    __shared__ float w1[G_][FD_];
    __shared__ float b1[G_];
    __shared__ float dimt[8];

    const int b = blockIdx.x / N_;
    const int q = blockIdx.x % N_;
    const int t = threadIdx.x;

    for (int i = t; i < G_ * FD_; i += 256) w1[i >> 6][i & 63] = fc1_w[i];
    if (t < G_) b1[t] = fc1_b[t];
    if (t < 8)  dimt[t] = powf(1000.0f, (float)t * 0.125f);

    const float* bq = &bbox[(b * N_ + q) * 4];
    const float qx0 = bq[0], qy0 = bq[1], qx1 = bq[2], qy1 = bq[3];
    const float bwq = qx1 - qx0 + 1.0f, bhq = qy1 - qy0 + 1.0f;
    const float cxq = 0.5f * (qx0 + qx1), cyq = 0.5f * (qy0 + qy1);

    __syncthreads();

    for (int idx = t; idx < N_ * 32; idx += 256) {
        const int k = idx >> 5;
        const int p = (idx >> 3) & 3;
        const int j = idx & 7;
        const float* bk = &bbox[(b * N_ + k) * 4];
        const float kx0 = bk[0], ky0 = bk[1], kx1 = bk[2], ky1 = bk[3];
        const float bwk = kx1 - kx0 + 1.0f, bhk = ky1 - ky0 + 1.0f;
        const float cxk = 0.5f * (kx0 + kx1), cyk = 0.5f * (ky0 + ky1);
        float pos;
        if      (p == 0) pos = logf(fmaxf(fabsf((cxq - cxk) / bwq), 1e-3f));
        else if (p == 1) pos = logf(fmaxf(fabsf((cyq - cyk) / bhq), 1e-3f));
        else if (p == 2) pos = logf(bwq / bwk);
        else             pos = logf(bhq / bhk);
        const float dv = 100.0f * pos / dimt[j];
        emb[k][p * 16 + j]     = sinf(dv);
        emb[k][p * 16 + 8 + j] = cosf(dv);
    }
    __syncthreads();

    for (int idx = t; idx < G_ * N_; idx += 256) {
        const int g = idx / N_;
        const int k = idx % N_;
        float acc = b1[g];
#pragma unroll
        for (int f = 0; f < FD_; ++f) acc += emb[k][f] * w1[g][f];
        const float aw = fmaxf(acc, 0.0f);
        logw[((b * N_ + q) * G_ + g) * N_ + k] = logf(fmaxf(aw, 1e-6f));
    }
}

// ---------------------------------------------------------------------------
// Attention: one block per (b,g). Wave-parallel softmax (4 lanes/row).
// ---------------------------------------------------------------------------
__global__ __launch_bounds__(256) void attn_kernel(
    const float* __restrict__ qbuf, const float* __restrict__ kbuf,
    const float* __restrict__ fkbuf, const float* __restrict__ logw,
    const unsigned char* __restrict__ mask8, const int* __restrict__ mask32,
    const int* __restrict__ flag, const float* __restrict__ feat,
    const float* __restrict__ conv_b, float* __restrict__ out)
{
    __shared__ float qs[N_][DG_ + 1];
    __shared__ float ks[N_][DG_ + 1];
    __shared__ float fs[N_][DG_ + 1];
    __shared__ float s[50][N_ + 1];

    const int b = blockIdx.x / G_;
    const int g = blockIdx.x % G_;
    const int t = threadIdx.x;
    const bool bytemask = (*flag != 0);
    const float scale = 0.17677669529663687f;  // 1/sqrt(32)

    for (int i = t; i < N_ * 8; i += 256) {
        const int n = i >> 3, c4 = (i & 7) * 4;
        const int gb = (b * N_ + n) * D_ + g * DG_ + c4;
        float4 v = *reinterpret_cast<const float4*>(&qbuf[gb]);
        qs[n][c4] = v.x; qs[n][c4 + 1] = v.y; qs[n][c4 + 2] = v.z; qs[n][c4 + 3] = v.w;
        float4 w = *reinterpret_cast<const float4*>(&kbuf[gb]);
        ks[n][c4] = w.x; ks[n][c4 + 1] = w.y; ks[n][c4 + 2] = w.z; ks[n][c4 + 3] = w.w;
        float4 f = *reinterpret_cast<const float4*>(&fkbuf[gb]);
        fs[n][c4] = f.x; fs[n][c4 + 1] = f.y; fs[n][c4 + 2] = f.z; fs[n][c4 + 3] = f.w;
    }
    __syncthreads();

    for (int h = 0; h < 2; ++h) {
        const int q0 = h * 50;
        // scores
        for (int idx = t; idx < 50 * N_; idx += 256) {
            const int qr = idx / N_, k = idx % N_;
            const int qi = q0 + qr;
            float acc = 0.0f;
#pragma unroll
            for (int d = 0; d < DG_; ++d) acc += qs[qi][d] * ks[k][d];
            const int base = ((b * N_ + qi) * G_ + g) * N_ + k;
            const float v = acc * scale + logw[base];
            const bool msk = bytemask ? (mask8[base] != 0) : (mask32[base] != 0);
            s[qr][k] = msk ? -1e9f : v;
        }
        __syncthreads();
        // wave-parallel row softmax: 4 lanes per row
        {
            const int r = t >> 2, ls = t & 3;
            if (r < 50) {
                float mx = -1e30f;
                for (int k = ls; k < N_; k += 4) mx = fmaxf(mx, s[r][k]);
                mx = fmaxf(mx, __shfl_xor(mx, 1));
                mx = fmaxf(mx, __shfl_xor(mx, 2));
                float sum = 0.0f;
                for (int k = ls; k < N_; k += 4) {
                    const float e = __expf(s[r][k] - mx);
                    s[r][k] = e; sum += e;
                }
                sum += __shfl_xor(sum, 1);
                sum += __shfl_xor(sum, 2);
                const float inv = 1.0f / sum;
                for (int k = ls; k < N_; k += 4) s[r][k] *= inv;
            }
        }
        __syncthreads();
        // PV + bias + residual + relu
        for (int idx = t; idx < 50 * DG_; idx += 256) {
            const int qr = idx / DG_, o = idx % DG_;
            const int qi = q0 + qr;
            float acc = 0.0f;
#pragma unroll 4
            for (int k = 0; k < N_; ++k) acc += s[qr][k] * fs[k][o];
            const int col = g * DG_ + o;
            const int gi = (b * N_ + qi) * D_ + col;
            const float r = feat[gi] + acc + conv_b[col];
            out[gi] = fmaxf(r, 0.0f);
        }
        __syncthreads();
    }
}

// ---------------------------------------------------------------------------
extern "C" void kernel_launch(void* const* d_in, const int* in_sizes, int n_in,
                              void* d_out, int out_size, void* d_ws, size_t ws_size,
                              hipStream_t stream)
{
    const float* feat   = (const float*)d_in[0];
    const float* bbox   = (const float*)d_in[1];
    const void*  maskp  = d_in[2];
    const float* fc1_w  = (const float*)d_in[3];
    const float* fc1_b  = (const float*)d_in[4];
    const float* q_w    = (const float*)d_in[5];
    const float* q_b    = (const float*)d_in[6];
    const float* k_w    = (const float*)d_in[7];
    const float* k_b    = (const float*)d_in[8];
    const float* conv_w = (const float*)d_in[9];
    const float* conv_b = (const float*)d_in[10];

    float* ws = (float*)d_ws;
    const int BN_D  = B_ * N_ * D_;          // 3,276,800
    const int BNGN  = B_ * N_ * G_ * N_;     // 10,240,000
    const int DD    = D_ * D_;               // 1,048,576
    float* qbuf  = ws;
    float* kbuf  = ws + BN_D;
    float* fkbuf = ws + 2 * BN_D;
    float* logw  = ws + 3 * BN_D;
    int*   flag  = (int*)(ws + 3 * BN_D + BNGN);

    // bf16 staging buffers alias logw (dead before pos_fc1 writes logw)
    unsigned short* featb = (unsigned short*)logw;
    unsigned short* wqb   = featb + BN_D;
    unsigned short* wkb   = wqb + DD;
    unsigned short* wcb   = wkb + DD;

    hipMemsetAsync(flag, 0, sizeof(int), stream);
    detect_mask_kernel<<<256, 256, 0, stream>>>((const unsigned int*)maskp,
                                                BNGN / 4, flag);

    cast_f32_bf16<<<BN_D / 8 / 256, 256, 0, stream>>>(feat, featb, BN_D / 8);
    cast_f32_bf16<<<DD / 8 / 256, 256, 0, stream>>>(q_w, wqb, DD / 8);
    cast_f32_bf16<<<DD / 8 / 256, 256, 0, stream>>>(k_w, wkb, DD / 8);
    cast_f32_bf16<<<DD / 8 / 256, 256, 0, stream>>>(conv_w, wcb, DD / 8);

    dim3 gg(B_ * N_ / 128, D_ / 128, 3);  // (25, 8, 3)
    mfma_gemm_nt<<<gg, 256, 0, stream>>>(featb, wqb, wkb, wcb, q_b, k_b,
                                         qbuf, kbuf, fkbuf);

    pos_fc1_kernel<<<B_ * N_, 256, 0, stream>>>(bbox, fc1_w, fc1_b, logw);

    attn_kernel<<<B_ * G_, 256, 0, stream>>>(qbuf, kbuf, fkbuf, logw,
                                             (const unsigned char*)maskp,
                                             (const int*)maskp, flag, feat,
                                             conv_b, (float*)d_out);
}

// Round 4
// 208.030 us; speedup vs baseline: 2.8838x; 1.4045x over previous
//
#include <hip/hip_runtime.h>
#include <math.h>

#define B_  32
#define N_  100
#define G_  32
#define D_  1024
#define DG_ 32
#define FD_ 64

typedef __attribute__((ext_vector_type(8))) short short8;
typedef __attribute__((ext_vector_type(8))) unsigned short ushort8;
typedef __attribute__((ext_vector_type(4))) float f32x4;

__device__ inline unsigned short f2bf(float f) {
    unsigned int x = __float_as_uint(f);
    unsigned int r = (x + 0x7fffu + ((x >> 16) & 1u)) >> 16;  // RNE
    return (unsigned short)r;
}

__device__ inline void load_lds16(const void* g, void* l) {
    __builtin_amdgcn_global_load_lds(
        (const __attribute__((address_space(1))) void*)g,
        (__attribute__((address_space(3))) void*)l, 16, 0, 0);
}

// ---------------------------------------------------------------------------
// Mask dtype detection (bool-byte vs int32).
// ---------------------------------------------------------------------------
__global__ __launch_bounds__(256) void detect_mask_kernel(
    const unsigned int* __restrict__ m, int nwords, int* __restrict__ flag)
{
    int v = 0;
    for (int i = blockIdx.x * 256 + threadIdx.x; i < nwords; i += gridDim.x * 256)
        v |= (m[i] > 1u) ? 1 : 0;
    if (__any(v) && (threadIdx.x & 63) == 0)
        atomicOr(flag, 1);
}

// ---------------------------------------------------------------------------
// f32 -> bf16 cast, 8 elems/thread.
// ---------------------------------------------------------------------------
__global__ __launch_bounds__(256) void cast_f32_bf16(
    const float* __restrict__ src, unsigned short* __restrict__ dst, int n8)
{
    const int i = blockIdx.x * 256 + threadIdx.x;
    if (i >= n8) return;
    const float4 a = reinterpret_cast<const float4*>(src)[i * 2 + 0];
    const float4 b = reinterpret_cast<const float4*>(src)[i * 2 + 1];
    ushort8 o;
    o[0] = f2bf(a.x); o[1] = f2bf(a.y); o[2] = f2bf(a.z); o[3] = f2bf(a.w);
    o[4] = f2bf(b.x); o[5] = f2bf(b.y); o[6] = f2bf(b.z); o[7] = f2bf(b.w);
    *reinterpret_cast<ushort8*>(&dst[i * 8]) = o;
}

// ---------------------------------------------------------------------------
// bf16 MFMA GEMM NT. z=0: q (bf16 out, q_b). z=1: k (bf16 out, k_b).
// z=2: fk (f32 out, no bias).
// ---------------------------------------------------------------------------
__global__ __launch_bounds__(256) void mfma_gemm_nt(
    const unsigned short* __restrict__ A,
    const unsigned short* __restrict__ Wq,
    const unsigned short* __restrict__ Wk,
    const unsigned short* __restrict__ Wc,
    const float* __restrict__ bq, const float* __restrict__ bk,
    unsigned short* __restrict__ Q16, unsigned short* __restrict__ K16,
    float* __restrict__ Cf)
{
    __shared__ short As[128 * 64];
    __shared__ short Bs[128 * 64];

    const int z = blockIdx.z;
    const unsigned short* W = (z == 0) ? Wq : (z == 1) ? Wk : Wc;

    const int m0 = blockIdx.x * 128;
    const int n0 = blockIdx.y * 128;
    const int t = threadIdx.x;
    const int lane = t & 63;
    const int wid = t >> 6;
    const int wr = wid >> 1, wc = wid & 1;

    f32x4 acc[4][4] = {};

    for (int k0 = 0; k0 < D_; k0 += 64) {
#pragma unroll
        for (int c = 0; c < 4; ++c) {
            const int idx16 = c * 256 + t;
            const int row = idx16 >> 3;
            const int colb = ((idx16 & 7) * 16) ^ ((row & 7) << 4);
            const char* ga = (const char*)(A + (size_t)(m0 + row) * D_ + k0) + colb;
            const char* gw = (const char*)(W + (size_t)(n0 + row) * D_ + k0) + colb;
            char* la = (char*)As + (c * 256 + wid * 64) * 16;
            char* lb = (char*)Bs + (c * 256 + wid * 64) * 16;
            load_lds16(ga, la);
            load_lds16(gw, lb);
        }
        __syncthreads();

#pragma unroll
        for (int ks = 0; ks < 2; ++ks) {
            short8 afr[4], bfr[4];
            const int kb = ks * 64 + (lane >> 4) * 16;
#pragma unroll
            for (int f = 0; f < 4; ++f) {
                const int am = wr * 64 + f * 16 + (lane & 15);
                afr[f] = *reinterpret_cast<const short8*>(
                    (const char*)As + am * 128 + (kb ^ ((am & 7) << 4)));
                const int bn = wc * 64 + f * 16 + (lane & 15);
                bfr[f] = *reinterpret_cast<const short8*>(
                    (const char*)Bs + bn * 128 + (kb ^ ((bn & 7) << 4)));
            }
#pragma unroll
            for (int i = 0; i < 4; ++i)
#pragma unroll
                for (int j = 0; j < 4; ++j)
                    acc[i][j] = __builtin_amdgcn_mfma_f32_16x16x32_bf16(
                        afr[i], bfr[j], acc[i][j], 0, 0, 0);
        }
        __syncthreads();
    }

    if (z == 2) {
#pragma unroll
        for (int j = 0; j < 4; ++j) {
            const int col = n0 + wc * 64 + j * 16 + (lane & 15);
#pragma unroll
            for (int i = 0; i < 4; ++i) {
                const int mbase = m0 + wr * 64 + i * 16 + (lane >> 4) * 4;
#pragma unroll
                for (int r = 0; r < 4; ++r)
                    Cf[(size_t)(mbase + r) * D_ + col] = acc[i][j][r];
            }
        }
    } else {
        unsigned short* O = (z == 0) ? Q16 : K16;
        const float* bias = (z == 0) ? bq : bk;
#pragma unroll
        for (int j = 0; j < 4; ++j) {
            const int col = n0 + wc * 64 + j * 16 + (lane & 15);
            const float bv = bias[col];
#pragma unroll
            for (int i = 0; i < 4; ++i) {
                const int mbase = m0 + wr * 64 + i * 16 + (lane >> 4) * 4;
#pragma unroll
                for (int r = 0; r < 4; ++r)
                    O[(size_t)(mbase + r) * D_ + col] = f2bf(acc[i][j][r] + bv);
            }
        }
    }
}

// ---------------------------------------------------------------------------
// Transpose-cast: fkbuf (B*N,1024) f32 -> fkT16 [(b*32+g)*32+dg][128] bf16,
// k index = box n (0..99), cols 100..127 zeroed. One block per (b,g).
// ---------------------------------------------------------------------------
__global__ __launch_bounds__(256) void fkt_kernel(
    const float* __restrict__ fkbuf, unsigned short* __restrict__ fkT)
{
    __shared__ float tile[DG_][N_ + 1];  // 32 x 101 -> pad 129? use N_+1=101
    const int bg = blockIdx.x;           // b*32+g
    const int b = bg >> 5, g = bg & 31;
    const int t = threadIdx.x;

    for (int i = t; i < N_ * DG_; i += 256) {
        const int n = i >> 5, dg = i & 31;
        tile[dg][n] = fkbuf[(size_t)(b * N_ + n) * D_ + g * DG_ + dg];
    }
    __syncthreads();

    for (int u = t; u < DG_ * 16; u += 256) {   // 32 rows x 16 segs of 8
        const int dg = u >> 4, seg = u & 15;
        ushort8 o;
#pragma unroll
        for (int j = 0; j < 8; ++j) {
            const int n = seg * 8 + j;
            o[j] = (n < N_) ? f2bf(tile[dg][n]) : (unsigned short)0;
        }
        *reinterpret_cast<ushort8*>(&fkT[((size_t)bg * DG_ + dg) * 128 + seg * 8]) = o;
    }
}

// ---------------------------------------------------------------------------
// Position embedding + fc1 + relu + log  ->  logw[b,q,g,k]
// ---------------------------------------------------------------------------
__global__ __launch_bounds__(256) void pos_fc1_kernel(
    const float* __restrict__ bbox, const float* __restrict__ fc1_w,
    const float* __restrict__ fc1_b, float* __restrict__ logw)
{
    __shared__ float emb[N_][FD_ + 4];   // 100 x 68 (16B-aligned rows)
    __shared__ float w1[G_][FD_ + 4];    // 32 x 68 (17g mod32 distinct banks)
    __shared__ float b1[G_];
    __shared__ float dimt[8];

    const int b = blockIdx.x / N_;
    const int q = blockIdx.x % N_;
    const int t = threadIdx.x;

    for (int i = t; i < G_ * FD_; i += 256) w1[i >> 6][i & 63] = fc1_w[i];
    if (t < G_) b1[t] = fc1_b[t];
    if (t < 8)  dimt[t] = powf(1000.0f, (float)t * 0.125f);

    const float* bq = &bbox[(b * N_ + q) * 4];
    const float qx0 = bq[0], qy0 = bq[1], qx1 = bq[2], qy1 = bq[3];
    const float bwq = qx1 - qx0 + 1.0f, bhq = qy1 - qy0 + 1.0f;
    const float cxq = 0.5f * (qx0 + qx1), cyq = 0.5f * (qy0 + qy1);

    __syncthreads();

    // Phase A
    for (int idx = t; idx < N_ * 32; idx += 256) {
        const int k = idx >> 5;
        const int p = (idx >> 3) & 3;
        const int j = idx & 7;
        const float* bk = &bbox[(b * N_ + k) * 4];
        const float kx0 = bk[0], ky0 = bk[1], kx1 = bk[2], ky1 = bk[3];
        const float bwk = kx1 - kx0 + 1.0f, bhk = ky1 - ky0 + 1.0f;
        const float cxk = 0.5f * (kx0 + kx1), cyk = 0.5f * (ky0 + ky1);
        float pos;
        if      (p == 0) pos = __logf(fmaxf(fabsf((cxq - cxk) / bwq), 1e-3f));
        else if (p == 1) pos = __logf(fmaxf(fabsf((cyq - cyk) / bhq), 1e-3f));
        else if (p == 2) pos = __logf(bwq / bwk);
        else             pos = __logf(bhq / bhk);
        const float dv = 100.0f * pos / dimt[j];
        emb[k][p * 16 + j]     = __sinf(dv);
        emb[k][p * 16 + 8 + j] = __cosf(dv);
    }
    __syncthreads();

    // Phase B: 2g x 2k register tile, lanes vary g (w1 conflict-free,
    // emb broadcast within 16-lane groups).
    const size_t obase = (size_t)(b * N_ + q) * G_ * N_;
    for (int u = t; u < 16 * 50; u += 256) {
        const int gp = u & 15, kp = u >> 4;
        const int g0 = gp, g1 = gp + 16;
        const int k0 = kp, k1 = kp + 50;
        float a00 = b1[g0], a10 = b1[g1], a01 = b1[g0], a11 = b1[g1];
#pragma unroll
        for (int f4 = 0; f4 < 16; ++f4) {
            const float4 e0 = *reinterpret_cast<const float4*>(&emb[k0][f4 * 4]);
            const float4 e1 = *reinterpret_cast<const float4*>(&emb[k1][f4 * 4]);
            const float4 w0 = *reinterpret_cast<const float4*>(&w1[g0][f4 * 4]);
            const float4 w2 = *reinterpret_cast<const float4*>(&w1[g1][f4 * 4]);
            a00 += e0.x * w0.x + e0.y * w0.y + e0.z * w0.z + e0.w * w0.w;
            a10 += e0.x * w2.x + e0.y * w2.y + e0.z * w2.z + e0.w * w2.w;
            a01 += e1.x * w0.x + e1.y * w0.y + e1.z * w0.z + e1.w * w0.w;
            a11 += e1.x * w2.x + e1.y * w2.y + e1.z * w2.z + e1.w * w2.w;
        }
        logw[obase + (size_t)g0 * N_ + k0] = __logf(fmaxf(fmaxf(a00, 0.0f), 1e-6f));
        logw[obase + (size_t)g1 * N_ + k0] = __logf(fmaxf(fmaxf(a10, 0.0f), 1e-6f));
        logw[obase + (size_t)g0 * N_ + k1] = __logf(fmaxf(fmaxf(a01, 0.0f), 1e-6f));
        logw[obase + (size_t)g1 * N_ + k1] = __logf(fmaxf(fmaxf(a11, 0.0f), 1e-6f));
    }
}

// ---------------------------------------------------------------------------
// MFMA attention: one block per (b,g), 4 waves. Wave w owns q-rows
// [32w, 32w+32). QK^T via direct-global bf16 frags; in-register softmax;
// P -> bf16 -> XOR-swizzled LDS; PV vs LDS-staged fkT. One barrier total.
// ---------------------------------------------------------------------------
__global__ __launch_bounds__(256) void attn_mfma(
    const unsigned short* __restrict__ qb, const unsigned short* __restrict__ kb,
    const unsigned short* __restrict__ fkT, const float* __restrict__ logw,
    const unsigned char* __restrict__ mask8, const int* __restrict__ mask32,
    const int* __restrict__ flag, const float* __restrict__ feat,
    const float* __restrict__ conv_b, float* __restrict__ out)
{
    __shared__ unsigned short Plds[128 * 128];  // [qrow][k] bf16, XOR swizzle
    __shared__ unsigned short Flds[DG_ * 128];  // [dg][k] bf16, XOR swizzle

    const int bg = blockIdx.x;
    const int b = bg >> 5, g = bg & 31;
    const int t = threadIdx.x;
    const int lane = t & 63;
    const int w = t >> 6;
    const int lo = lane & 15, hi = lane >> 4;
    const bool bytemask = (*flag != 0);
    const float scale = 0.17677669529663687f;  // 1/sqrt(32)

    // ---- phase 0: zero P; stage fkT -> Flds (swizzled) ----
    {
        short8 zs = {};
#pragma unroll
        for (int i = 0; i < 8; ++i)
            *reinterpret_cast<short8*>(&Plds[(t + i * 256) * 8]) = zs;
#pragma unroll
        for (int i = 0; i < 2; ++i) {
            const int u = t + i * 256;                 // 512 units of 16B
            const int dg = u >> 4, seg = u & 15;
            const ushort8 v = *reinterpret_cast<const ushort8*>(
                &fkT[((size_t)bg * DG_ + dg) * 128 + seg * 8]);
            const int byte = (dg * 256 + seg * 16) ^ ((dg & 7) << 4);
            *reinterpret_cast<ushort8*>((char*)Flds + byte) = v;
        }
    }

    // ---- QK^T fragments direct from global ----
    short8 qf[2], kf[7];
#pragma unroll
    for (int mtl = 0; mtl < 2; ++mtl) {
        const int row = w * 32 + mtl * 16 + lo;
        const int rc = row < N_ ? row : N_ - 1;
        qf[mtl] = *reinterpret_cast<const short8*>(
            qb + (size_t)(b * N_ + rc) * D_ + g * DG_ + hi * 8);
    }
#pragma unroll
    for (int ct = 0; ct < 7; ++ct) {
        const int kr = ct * 16 + lo;
        const int krc = kr < N_ ? kr : N_ - 1;
        kf[ct] = *reinterpret_cast<const short8*>(
            kb + (size_t)(b * N_ + krc) * D_ + g * DG_ + hi * 8);
    }

    __syncthreads();   // P zeroed + Flds staged (needed later; barrier here
                       // overlaps staging with the frag loads above)

    f32x4 s[2][7];
#pragma unroll
    for (int mtl = 0; mtl < 2; ++mtl)
#pragma unroll
        for (int ct = 0; ct < 7; ++ct) {
            f32x4 z = {};
            s[mtl][ct] = __builtin_amdgcn_mfma_f32_16x16x32_bf16(
                qf[mtl], kf[ct], z, 0, 0, 0);
        }

    // ---- scale + logw + mask ----
#pragma unroll
    for (int mtl = 0; mtl < 2; ++mtl) {
        const int qr0 = w * 32 + mtl * 16 + hi * 4;
#pragma unroll
        for (int ct = 0; ct < 7; ++ct) {
            const int k = ct * 16 + lo;
            const bool kvalid = (k < N_);
            const int kc = kvalid ? k : N_ - 1;
#pragma unroll
            for (int r = 0; r < 4; ++r) {
                const int q = qr0 + r;
                const int qc = q < N_ ? q : N_ - 1;
                const size_t idx = ((size_t)(b * N_ + qc) * G_ + g) * N_ + kc;
                const float lw = logw[idx];
                const bool m = bytemask ? (mask8[idx] != 0) : (mask32[idx] != 0);
                const float v = s[mtl][ct][r] * scale + lw;
                s[mtl][ct][r] = (kvalid && !m) ? v : -1e30f;
            }
        }
    }

    // ---- in-register row softmax (rows = (mtl, hi*4+r)) ----
    float mx[2][4], sm[2][4];
#pragma unroll
    for (int mtl = 0; mtl < 2; ++mtl) {
        f32x4 mv = s[mtl][0];
#pragma unroll
        for (int ct = 1; ct < 7; ++ct) {
#pragma unroll
            for (int r = 0; r < 4; ++r) mv[r] = fmaxf(mv[r], s[mtl][ct][r]);
        }
#pragma unroll
        for (int r = 0; r < 4; ++r) {
            float m = mv[r];
            m = fmaxf(m, __shfl_xor(m, 1));
            m = fmaxf(m, __shfl_xor(m, 2));
            m = fmaxf(m, __shfl_xor(m, 4));
            m = fmaxf(m, __shfl_xor(m, 8));
            mx[mtl][r] = m;
        }
    }
#pragma unroll
    for (int mtl = 0; mtl < 2; ++mtl) {
        f32x4 sv = {};
#pragma unroll
        for (int ct = 0; ct < 7; ++ct)
#pragma unroll
            for (int r = 0; r < 4; ++r) {
                const float e = __expf(s[mtl][ct][r] - mx[mtl][r]);
                s[mtl][ct][r] = e;
                sv[r] += e;
            }
#pragma unroll
        for (int r = 0; r < 4; ++r) {
            float ss = sv[r];
            ss += __shfl_xor(ss, 1);
            ss += __shfl_xor(ss, 2);
            ss += __shfl_xor(ss, 4);
            ss += __shfl_xor(ss, 8);
            sm[mtl][r] = 1.0f / ss;
        }
    }

    // ---- P -> bf16 -> LDS (rows are wave-private; no barrier needed) ----
#pragma unroll
    for (int mtl = 0; mtl < 2; ++mtl) {
        const int qr0 = w * 32 + mtl * 16 + hi * 4;
#pragma unroll
        for (int ct = 0; ct < 7; ++ct) {
            const int col = ct * 16 + lo;
#pragma unroll
            for (int r = 0; r < 4; ++r) {
                const int row = qr0 + r;
                const int byte = row * 256 + ((col * 2) ^ ((row & 7) << 4));
                *(unsigned short*)((char*)Plds + byte) =
                    f2bf(s[mtl][ct][r] * sm[mtl][r]);
            }
        }
    }

    // ---- PV: out[q][dg] = sum_k P[q][k] * FKT[dg][k] ----
    f32x4 o[2][2] = {};
#pragma unroll
    for (int ks = 0; ks < 4; ++ks) {
        short8 pa[2], fb[2];
#pragma unroll
        for (int mtl = 0; mtl < 2; ++mtl) {
            const int prow = w * 32 + mtl * 16 + lo;
            const int byte = prow * 256 + ((ks * 64 + hi * 16) ^ ((prow & 7) << 4));
            pa[mtl] = *reinterpret_cast<const short8*>((const char*)Plds + byte);
        }
#pragma unroll
        for (int nt = 0; nt < 2; ++nt) {
            const int dg = nt * 16 + lo;
            const int byte = dg * 256 + ((ks * 64 + hi * 16) ^ ((dg & 7) << 4));
            fb[nt] = *reinterpret_cast<const short8*>((const char*)Flds + byte);
        }
#pragma unroll
        for (int mtl = 0; mtl < 2; ++mtl)
#pragma unroll
            for (int nt = 0; nt < 2; ++nt)
                o[mtl][nt] = __builtin_amdgcn_mfma_f32_16x16x32_bf16(
                    pa[mtl], fb[nt], o[mtl][nt], 0, 0, 0);
    }

    // ---- epilogue: + conv_b + residual feat, relu ----
#pragma unroll
    for (int mtl = 0; mtl < 2; ++mtl) {
        const int qr0 = w * 32 + mtl * 16 + hi * 4;
#pragma unroll
        for (int nt = 0; nt < 2; ++nt) {
            const int col = g * DG_ + nt * 16 + lo;
            const float cb = conv_b[col];
#pragma unroll
            for (int r = 0; r < 4; ++r) {
                const int q = qr0 + r;
                if (q < N_) {
                    const size_t gi = (size_t)(b * N_ + q) * D_ + col;
                    out[gi] = fmaxf(feat[gi] + o[mtl][nt][r] + cb, 0.0f);
                }
            }
        }
    }
}

// ---------------------------------------------------------------------------
extern "C" void kernel_launch(void* const* d_in, const int* in_sizes, int n_in,
                              void* d_out, int out_size, void* d_ws, size_t ws_size,
                              hipStream_t stream)
{
    const float* feat   = (const float*)d_in[0];
    const float* bbox   = (const float*)d_in[1];
    const void*  maskp  = d_in[2];
    const float* fc1_w  = (const float*)d_in[3];
    const float* fc1_b  = (const float*)d_in[4];
    const float* q_w    = (const float*)d_in[5];
    const float* q_b    = (const float*)d_in[6];
    const float* k_w    = (const float*)d_in[7];
    const float* k_b    = (const float*)d_in[8];
    const float* conv_w = (const float*)d_in[9];
    const float* conv_b = (const float*)d_in[10];

    float* ws = (float*)d_ws;
    const int BN_D  = B_ * N_ * D_;          // 3,276,800
    const int BNGN  = B_ * N_ * G_ * N_;     // 10,240,000
    const int DD    = D_ * D_;               // 1,048,576

    unsigned short* qb16  = (unsigned short*)ws;                    // BN_D shorts
    unsigned short* kb16  = qb16 + BN_D;                            // BN_D shorts
    float* fkbuf = ws + BN_D;                                       // after q+k (BN_D floats)
    unsigned short* fkT16 = (unsigned short*)(ws + 2 * BN_D);       // 32768*128 shorts
    float* logw  = ws + 2 * BN_D + (32768 * 128) / 2;               // BNGN floats
    int*   flag  = (int*)(logw + BNGN);

    // bf16 cast staging aliases logw region (dead before pos_fc1 runs)
    unsigned short* featb = (unsigned short*)logw;
    unsigned short* wqb   = featb + BN_D;
    unsigned short* wkb   = wqb + DD;
    unsigned short* wcb   = wkb + DD;

    hipMemsetAsync(flag, 0, sizeof(int), stream);
    detect_mask_kernel<<<256, 256, 0, stream>>>((const unsigned int*)maskp,
                                                BNGN / 4, flag);

    cast_f32_bf16<<<BN_D / 8 / 256, 256, 0, stream>>>(feat, featb, BN_D / 8);
    cast_f32_bf16<<<DD / 8 / 256, 256, 0, stream>>>(q_w, wqb, DD / 8);
    cast_f32_bf16<<<DD / 8 / 256, 256, 0, stream>>>(k_w, wkb, DD / 8);
    cast_f32_bf16<<<DD / 8 / 256, 256, 0, stream>>>(conv_w, wcb, DD / 8);

    dim3 gg(B_ * N_ / 128, D_ / 128, 3);  // (25, 8, 3)
    mfma_gemm_nt<<<gg, 256, 0, stream>>>(featb, wqb, wkb, wcb, q_b, k_b,
                                         qb16, kb16, fkbuf);

    fkt_kernel<<<B_ * G_, 256, 0, stream>>>(fkbuf, fkT16);

    pos_fc1_kernel<<<B_ * N_, 256, 0, stream>>>(bbox, fc1_w, fc1_b, logw);

    attn_mfma<<<B_ * G_, 256, 0, stream>>>(qb16, kb16, fkT16, logw,
                                           (const unsigned char*)maskp,
                                           (const int*)maskp, flag, feat,
                                           conv_b, (float*)d_out);
}

// Round 5
// 144.816 us; speedup vs baseline: 4.1426x; 1.4365x over previous
//
#include <hip/hip_runtime.h>
#include <math.h>

#define B_  32
#define N_  100
#define G_  32
#define D_  1024
#define DG_ 32
#define FD_ 64

typedef __attribute__((ext_vector_type(8))) short short8;
typedef __attribute__((ext_vector_type(8))) unsigned short ushort8;
typedef __attribute__((ext_vector_type(4))) unsigned short ushort4v;
typedef __attribute__((ext_vector_type(4))) float f32x4;

__device__ inline unsigned short f2bf(float f) {
    unsigned int x = __float_as_uint(f);
    unsigned int r = (x + 0x7fffu + ((x >> 16) & 1u)) >> 16;  // RNE
    return (unsigned short)r;
}
__device__ inline unsigned short f2h(float f) {
    _Float16 h = (_Float16)f;
    return __builtin_bit_cast(unsigned short, h);
}
__device__ inline float h2f(unsigned short u) {
    return (float)__builtin_bit_cast(_Float16, u);
}
__device__ inline void load_lds16(const void* g, void* l) {
    __builtin_amdgcn_global_load_lds(
        (const __attribute__((address_space(1))) void*)g,
        (__attribute__((address_space(3))) void*)l, 16, 0, 0);
}

// ---------------------------------------------------------------------------
// Mask dtype detection (bool-byte vs int32).
// ---------------------------------------------------------------------------
__global__ __launch_bounds__(256) void detect_mask_kernel(
    const unsigned int* __restrict__ m, int nwords, int* __restrict__ flag)
{
    int v = 0;
    for (int i = blockIdx.x * 256 + threadIdx.x; i < nwords; i += gridDim.x * 256)
        v |= (m[i] > 1u) ? 1 : 0;
    if (__any(v) && (threadIdx.x & 63) == 0)
        atomicOr(flag, 1);
}

// ---------------------------------------------------------------------------
// f32 -> bf16 cast, 8 elems/thread.
// ---------------------------------------------------------------------------
__global__ __launch_bounds__(256) void cast_f32_bf16(
    const float* __restrict__ src, unsigned short* __restrict__ dst, int n8)
{
    const int i = blockIdx.x * 256 + threadIdx.x;
    if (i >= n8) return;
    const float4 a = reinterpret_cast<const float4*>(src)[i * 2 + 0];
    const float4 b = reinterpret_cast<const float4*>(src)[i * 2 + 1];
    ushort8 o;
    o[0] = f2bf(a.x); o[1] = f2bf(a.y); o[2] = f2bf(a.z); o[3] = f2bf(a.w);
    o[4] = f2bf(b.x); o[5] = f2bf(b.y); o[6] = f2bf(b.z); o[7] = f2bf(b.w);
    *reinterpret_cast<ushort8*>(&dst[i * 8]) = o;
}

// ---------------------------------------------------------------------------
// bf16 MFMA GEMM NT. z=0: q(+q_b). z=1: k(+k_b). z=2: fk (no bias).
// All outputs bf16.
// ---------------------------------------------------------------------------
__global__ __launch_bounds__(256) void mfma_gemm_nt(
    const unsigned short* __restrict__ A,
    const unsigned short* __restrict__ Wq,
    const unsigned short* __restrict__ Wk,
    const unsigned short* __restrict__ Wc,
    const float* __restrict__ bq, const float* __restrict__ bk,
    unsigned short* __restrict__ Q16, unsigned short* __restrict__ K16,
    unsigned short* __restrict__ F16)
{
    __shared__ short As[128 * 64];
    __shared__ short Bs[128 * 64];

    const int z = blockIdx.z;
    const unsigned short* W = (z == 0) ? Wq : (z == 1) ? Wk : Wc;
    const float* bias        = (z == 0) ? bq : (z == 1) ? bk : nullptr;
    unsigned short* O        = (z == 0) ? Q16 : (z == 1) ? K16 : F16;

    const int m0 = blockIdx.x * 128;
    const int n0 = blockIdx.y * 128;
    const int t = threadIdx.x;
    const int lane = t & 63;
    const int wid = t >> 6;
    const int wr = wid >> 1, wc = wid & 1;

    f32x4 acc[4][4] = {};

    for (int k0 = 0; k0 < D_; k0 += 64) {
#pragma unroll
        for (int c = 0; c < 4; ++c) {
            const int idx16 = c * 256 + t;
            const int row = idx16 >> 3;
            const int colb = ((idx16 & 7) * 16) ^ ((row & 7) << 4);
            const char* ga = (const char*)(A + (size_t)(m0 + row) * D_ + k0) + colb;
            const char* gw = (const char*)(W + (size_t)(n0 + row) * D_ + k0) + colb;
            char* la = (char*)As + (c * 256 + wid * 64) * 16;
            char* lb = (char*)Bs + (c * 256 + wid * 64) * 16;
            load_lds16(ga, la);
            load_lds16(gw, lb);
        }
        __syncthreads();

#pragma unroll
        for (int ks = 0; ks < 2; ++ks) {
            short8 afr[4], bfr[4];
            const int kb = ks * 64 + (lane >> 4) * 16;
#pragma unroll
            for (int f = 0; f < 4; ++f) {
                const int am = wr * 64 + f * 16 + (lane & 15);
                afr[f] = *reinterpret_cast<const short8*>(
                    (const char*)As + am * 128 + (kb ^ ((am & 7) << 4)));
                const int bn = wc * 64 + f * 16 + (lane & 15);
                bfr[f] = *reinterpret_cast<const short8*>(
                    (const char*)Bs + bn * 128 + (kb ^ ((bn & 7) << 4)));
            }
#pragma unroll
            for (int i = 0; i < 4; ++i)
#pragma unroll
                for (int j = 0; j < 4; ++j)
                    acc[i][j] = __builtin_amdgcn_mfma_f32_16x16x32_bf16(
                        afr[i], bfr[j], acc[i][j], 0, 0, 0);
        }
        __syncthreads();
    }

#pragma unroll
    for (int j = 0; j < 4; ++j) {
        const int col = n0 + wc * 64 + j * 16 + (lane & 15);
        const float bv = bias ? bias[col] : 0.0f;
#pragma unroll
        for (int i = 0; i < 4; ++i) {
            const int mbase = m0 + wr * 64 + i * 16 + (lane >> 4) * 4;
#pragma unroll
            for (int r = 0; r < 4; ++r)
                O[(size_t)(mbase + r) * D_ + col] = f2bf(acc[i][j][r] + bv);
        }
    }
}

// ---------------------------------------------------------------------------
// fkT: fk16 (B*N,1024) bf16 -> fkT[(b*32+g)*32+dg][128] bf16, cols=box n,
// n>=100 zero, 16B granules pre-swizzled by ^(dg&7). One block per (b,g).
// ---------------------------------------------------------------------------
__global__ __launch_bounds__(256) void fkt_kernel(
    const unsigned short* __restrict__ fk16, unsigned short* __restrict__ fkT)
{
    __shared__ unsigned short tile[DG_][N_ + 4];
    const int bg = blockIdx.x;
    const int b = bg >> 5, g = bg & 31;
    const int t = threadIdx.x;

    for (int i = t; i < N_ * 4; i += 256) {
        const int n = i >> 2, dg0 = (i & 3) * 8;
        const ushort8 v = *reinterpret_cast<const ushort8*>(
            fk16 + (size_t)(b * N_ + n) * D_ + g * DG_ + dg0);
#pragma unroll
        for (int j = 0; j < 8; ++j) tile[dg0 + j][n] = v[j];
    }
    __syncthreads();

    for (int u = t; u < DG_ * 16; u += 256) {
        const int dg = u >> 4, seg = u & 15;
        ushort8 o;
#pragma unroll
        for (int j = 0; j < 8; ++j) {
            const int n = seg * 8 + j;
            o[j] = (n < N_) ? tile[dg][n] : (unsigned short)0;
        }
        *reinterpret_cast<ushort8*>(
            fkT + ((size_t)bg * DG_ + dg) * 128 + (seg ^ (dg & 7)) * 8) = o;
    }
}

// ---------------------------------------------------------------------------
// pos_fc1: position embedding (f16 LDS) + fc1 via f16 MFMA + relu/log +
// mask fusion -> wm[b][g][q][128] f16, granule-pre-swizzled by ^(q&7).
// Masked / k>=100 cells = -65504. One block per (b,q), 4 waves.
// ---------------------------------------------------------------------------
__global__ __launch_bounds__(256) void pos_fc1_kernel(
    const float* __restrict__ bbox, const float* __restrict__ fc1_w,
    const float* __restrict__ fc1_b,
    const unsigned char* __restrict__ mask8, const int* __restrict__ mask32,
    const int* __restrict__ flag, unsigned short* __restrict__ wm)
{
    __shared__ unsigned short embh[112 * 72];   // [k-box][f], f16, pad 72
    __shared__ unsigned short w1h[G_ * 72];     // [g][f], f16
    __shared__ float b1[G_];
    __shared__ float dimt[8];

    const int b = blockIdx.x / N_;
    const int q = blockIdx.x % N_;
    const int t = threadIdx.x;
    const int lane = t & 63;
    const int w = t >> 6;
    const int lo = lane & 15, hi = lane >> 4;

    for (int i = t; i < G_ * FD_; i += 256)
        w1h[(i >> 6) * 72 + (i & 63)] = f2h(fc1_w[i]);
    if (t < G_) b1[t] = fc1_b[t];
    if (t < 8)  dimt[t] = powf(1000.0f, (float)t * 0.125f);
    for (int i = t; i < 12 * 64; i += 256)      // zero emb rows 100..111
        embh[(100 + (i >> 6)) * 72 + (i & 63)] = 0;

    const float* bq = &bbox[(b * N_ + q) * 4];
    const float qx0 = bq[0], qy0 = bq[1], qx1 = bq[2], qy1 = bq[3];
    const float bwq = qx1 - qx0 + 1.0f, bhq = qy1 - qy0 + 1.0f;
    const float cxq = 0.5f * (qx0 + qx1), cyq = 0.5f * (qy0 + qy1);

    __syncthreads();

    // Phase A: emb[k][f] f16
    for (int idx = t; idx < N_ * 32; idx += 256) {
        const int k = idx >> 5;
        const int p = (idx >> 3) & 3;
        const int j = idx & 7;
        const float* bk = &bbox[(b * N_ + k) * 4];
        const float kx0 = bk[0], ky0 = bk[1], kx1 = bk[2], ky1 = bk[3];
        const float bwk = kx1 - kx0 + 1.0f, bhk = ky1 - ky0 + 1.0f;
        const float cxk = 0.5f * (kx0 + kx1), cyk = 0.5f * (ky0 + ky1);
        float pos;
        if      (p == 0) pos = __logf(fmaxf(fabsf((cxq - cxk) / bwq), 1e-3f));
        else if (p == 1) pos = __logf(fmaxf(fabsf((cyq - cyk) / bhq), 1e-3f));
        else if (p == 2) pos = __logf(bwq / bwk);
        else             pos = __logf(bhq / bhk);
        const float dv = 100.0f * pos / dimt[j];
        embh[k * 72 + p * 16 + j]     = f2h(__sinf(dv));
        embh[k * 72 + p * 16 + 8 + j] = f2h(__cosf(dv));
    }
    __syncthreads();

    // Phase B: per wave, tiles of the 112(k) x 32(g) fc1 matmul via MFMA.
    const bool bytemask = (*flag != 0);
    const int xq = q & 7;
    for (int tid = w; tid < 14; tid += 4) {
        const int mt = tid >> 1, nt = tid & 1;
        f32x4 d = {};
#pragma unroll
        for (int ks = 0; ks < 2; ++ks) {
            const short8 af = *reinterpret_cast<const short8*>(
                embh + (mt * 16 + lo) * 72 + ks * 32 + hi * 8);
            const short8 bf = *reinterpret_cast<const short8*>(
                w1h + (nt * 16 + lo) * 72 + ks * 32 + hi * 8);
            d = __builtin_amdgcn_mfma_f32_16x16x32_f16(af, bf, d, 0, 0, 0);
        }
        const int g = nt * 16 + lo;
        const int k0 = mt * 16 + hi * 4;   // 4-aligned; k0<100 => all 4 valid
        const float bb = b1[g];
        unsigned int mby = 0;
        uint4 mi = {};
        if (k0 < N_) {
            const size_t midx = ((size_t)(b * N_ + q) * G_ + g) * N_ + k0;
            if (bytemask) mby = *(const unsigned int*)(mask8 + midx);
            else          mi  = *(const uint4*)(mask32 + midx);
        }
        ushort4v ov;
#pragma unroll
        for (int r = 0; r < 4; ++r) {
            const int k = k0 + r;
            const bool msk = bytemask
                ? (((mby >> (8 * r)) & 0xffu) != 0u)
                : ((r == 0 ? mi.x : r == 1 ? mi.y : r == 2 ? mi.z : mi.w) != 0u);
            const float aff = d[r] + bb;
            const float lv = __logf(fmaxf(fmaxf(aff, 0.0f), 1e-6f));
            ov[r] = f2h((k >= N_ || msk) ? -65504.0f : lv);
        }
        const size_t row = (size_t)(b * G_ + g) * N_ + q;
        char* dst = (char*)wm + row * 256 + ((2 * k0) ^ (xq << 4));
        *reinterpret_cast<ushort4v*>(dst) = ov;
    }
}

// ---------------------------------------------------------------------------
// MFMA attention: one block per (b,g), 4 waves, one barrier.
// PW LDS buffer: rows 0..99 staged wmask (f16, swizzled); after score reads,
// overwritten in-place per wave with P (bf16, same swizzle). FL = fkT staged.
// ---------------------------------------------------------------------------
__global__ __launch_bounds__(256) void attn_mfma(
    const unsigned short* __restrict__ qb, const unsigned short* __restrict__ kb,
    const unsigned short* __restrict__ fkT, const unsigned short* __restrict__ wm,
    const float* __restrict__ feat, const float* __restrict__ conv_b,
    float* __restrict__ out)
{
    __shared__ unsigned short PW[128 * 128];   // 32KB
    __shared__ unsigned short FL[DG_ * 128];   // 8KB

    const int bg = blockIdx.x;
    const int b = bg >> 5, g = bg & 31;
    const int t = threadIdx.x;
    const int lane = t & 63;
    const int w = t >> 6;
    const int lo = lane & 15, hi = lane >> 4;
    const float scale = 0.17677669529663687f;  // 1/sqrt(32)

    // ---- stage wmask (1600 x 16B) and fkT (512 x 16B), both linear ----
    {
        const char* src = (const char*)(wm + (size_t)bg * N_ * 128);
        for (int u = t; u < 1600; u += 256)
            load_lds16(src + u * 16, (char*)PW + u * 16);
        const char* fsrc = (const char*)(fkT + (size_t)bg * DG_ * 128);
        for (int u = t; u < 512; u += 256)
            load_lds16(fsrc + u * 16, (char*)FL + u * 16);
    }

    // ---- Q/K fragments direct from global bf16 ----
    short8 qf[2], kf[7];
#pragma unroll
    for (int mtl = 0; mtl < 2; ++mtl) {
        const int row = w * 32 + mtl * 16 + lo;
        const int rc = row < N_ ? row : N_ - 1;
        qf[mtl] = *reinterpret_cast<const short8*>(
            qb + (size_t)(b * N_ + rc) * D_ + g * DG_ + hi * 8);
    }
#pragma unroll
    for (int ct = 0; ct < 7; ++ct) {
        const int kr = ct * 16 + lo;
        const int krc = kr < N_ ? kr : N_ - 1;
        kf[ct] = *reinterpret_cast<const short8*>(
            kb + (size_t)(b * N_ + krc) * D_ + g * DG_ + hi * 8);
    }

    __syncthreads();   // staging complete

    // ---- QK^T ----
    f32x4 s[2][7];
#pragma unroll
    for (int mtl = 0; mtl < 2; ++mtl)
#pragma unroll
        for (int ct = 0; ct < 7; ++ct) {
            f32x4 z = {};
            s[mtl][ct] = __builtin_amdgcn_mfma_f32_16x16x32_bf16(
                qf[mtl], kf[ct], z, 0, 0, 0);
        }

    // ---- scale + wmask (masked cells already -65504 in wmask) ----
#pragma unroll
    for (int mtl = 0; mtl < 2; ++mtl) {
        const int qr0 = w * 32 + mtl * 16 + hi * 4;
#pragma unroll
        for (int ct = 0; ct < 7; ++ct) {
            const int k = ct * 16 + lo;
#pragma unroll
            for (int r = 0; r < 4; ++r) {
                const int row = qr0 + r;
                const float wv = h2f(*(const unsigned short*)(
                    (const char*)PW + row * 256 + ((2 * k) ^ ((row & 7) << 4))));
                s[mtl][ct][r] = s[mtl][ct][r] * scale + wv;
            }
        }
    }

    // ---- in-register row softmax ----
    float sm[2][4];
#pragma unroll
    for (int mtl = 0; mtl < 2; ++mtl) {
        f32x4 mv = s[mtl][0];
#pragma unroll
        for (int ct = 1; ct < 7; ++ct)
#pragma unroll
            for (int r = 0; r < 4; ++r) mv[r] = fmaxf(mv[r], s[mtl][ct][r]);
        float mx[4];
#pragma unroll
        for (int r = 0; r < 4; ++r) {
            float m = mv[r];
            m = fmaxf(m, __shfl_xor(m, 1));
            m = fmaxf(m, __shfl_xor(m, 2));
            m = fmaxf(m, __shfl_xor(m, 4));
            m = fmaxf(m, __shfl_xor(m, 8));
            mx[r] = m;
        }
        f32x4 sv = {};
#pragma unroll
        for (int ct = 0; ct < 7; ++ct)
#pragma unroll
            for (int r = 0; r < 4; ++r) {
                const float e = __expf(s[mtl][ct][r] - mx[r]);
                s[mtl][ct][r] = e;
                sv[r] += e;
            }
#pragma unroll
        for (int r = 0; r < 4; ++r) {
            float ss = sv[r];
            ss += __shfl_xor(ss, 1);
            ss += __shfl_xor(ss, 2);
            ss += __shfl_xor(ss, 4);
            ss += __shfl_xor(ss, 8);
            sm[mtl][r] = 1.0f / ss;
        }
    }

    // ---- P -> bf16 -> PW in-place (wave-private rows; dep-ordered) ----
#pragma unroll
    for (int mtl = 0; mtl < 2; ++mtl) {
        const int qr0 = w * 32 + mtl * 16 + hi * 4;
#pragma unroll
        for (int ct = 0; ct < 7; ++ct) {
            const int col = ct * 16 + lo;
#pragma unroll
            for (int r = 0; r < 4; ++r) {
                const int row = qr0 + r;
                *(unsigned short*)((char*)PW + row * 256 +
                                   ((2 * col) ^ ((row & 7) << 4))) =
                    f2bf(s[mtl][ct][r] * sm[mtl][r]);
            }
        }
    }
    // zero-fill pad granules 14,15 of this wave's 32 rows (k in [112,128))
    {
        const int zr = w * 32 + (lane & 31);
        const int zg = 14 + (lane >> 5);
        short8 zs = {};
        *reinterpret_cast<short8*>(
            (char*)PW + zr * 256 + ((zg * 16) ^ ((zr & 7) << 4))) = zs;
    }

    // ---- PV: out[q][dg] = sum_k P[q][k] * FK[dg][k] ----
    f32x4 o[2][2] = {};
#pragma unroll
    for (int ks = 0; ks < 4; ++ks) {
        short8 pa[2], fb[2];
#pragma unroll
        for (int mtl = 0; mtl < 2; ++mtl) {
            const int prow = w * 32 + mtl * 16 + lo;
            pa[mtl] = *reinterpret_cast<const short8*>(
                (const char*)PW + prow * 256 +
                ((ks * 64 + hi * 16) ^ ((prow & 7) << 4)));
        }
#pragma unroll
        for (int nt = 0; nt < 2; ++nt) {
            const int dg = nt * 16 + lo;
            fb[nt] = *reinterpret_cast<const short8*>(
                (const char*)FL + dg * 256 +
                ((ks * 64 + hi * 16) ^ ((dg & 7) << 4)));
        }
#pragma unroll
        for (int mtl = 0; mtl < 2; ++mtl)
#pragma unroll
            for (int nt = 0; nt < 2; ++nt)
                o[mtl][nt] = __builtin_amdgcn_mfma_f32_16x16x32_bf16(
                    pa[mtl], fb[nt], o[mtl][nt], 0, 0, 0);
    }

    // ---- epilogue: + conv_b + residual, relu ----
#pragma unroll
    for (int mtl = 0; mtl < 2; ++mtl) {
        const int qr0 = w * 32 + mtl * 16 + hi * 4;
#pragma unroll
        for (int nt = 0; nt < 2; ++nt) {
            const int col = g * DG_ + nt * 16 + lo;
            const float cb = conv_b[col];
#pragma unroll
            for (int r = 0; r < 4; ++r) {
                const int q = qr0 + r;
                if (q < N_) {
                    const size_t gi = (size_t)(b * N_ + q) * D_ + col;
                    out[gi] = fmaxf(feat[gi] + o[mtl][nt][r] + cb, 0.0f);
                }
            }
        }
    }
}

// ---------------------------------------------------------------------------
extern "C" void kernel_launch(void* const* d_in, const int* in_sizes, int n_in,
                              void* d_out, int out_size, void* d_ws, size_t ws_size,
                              hipStream_t stream)
{
    const float* feat   = (const float*)d_in[0];
    const float* bbox   = (const float*)d_in[1];
    const void*  maskp  = d_in[2];
    const float* fc1_w  = (const float*)d_in[3];
    const float* fc1_b  = (const float*)d_in[4];
    const float* q_w    = (const float*)d_in[5];
    const float* q_b    = (const float*)d_in[6];
    const float* k_w    = (const float*)d_in[7];
    const float* k_b    = (const float*)d_in[8];
    const float* conv_w = (const float*)d_in[9];
    const float* conv_b = (const float*)d_in[10];

    const int BN_D  = B_ * N_ * D_;          // 3,276,800
    const int BNGN  = B_ * N_ * G_ * N_;     // 10,240,000
    const int DD    = D_ * D_;               // 1,048,576
    const int FKT_N = B_ * G_ * DG_ * 128;   // 4,194,304
    const int WM_N  = B_ * G_ * N_ * 128;    // 13,107,200

    unsigned short* ws16 = (unsigned short*)d_ws;
    unsigned short* qb16  = ws16;
    unsigned short* kb16  = qb16 + BN_D;
    unsigned short* fk16  = kb16 + BN_D;
    unsigned short* fkT16 = fk16 + BN_D;
    unsigned short* wm    = fkT16 + FKT_N;
    int* flag = (int*)(wm + WM_N);

    // bf16 cast staging aliases wm (dead before pos_fc1 writes wm)
    unsigned short* featb = wm;
    unsigned short* wqb   = featb + BN_D;
    unsigned short* wkb   = wqb + DD;
    unsigned short* wcb   = wkb + DD;

    hipMemsetAsync(flag, 0, sizeof(int), stream);
    detect_mask_kernel<<<256, 256, 0, stream>>>((const unsigned int*)maskp,
                                                BNGN / 4, flag);

    cast_f32_bf16<<<BN_D / 8 / 256, 256, 0, stream>>>(feat, featb, BN_D / 8);
    cast_f32_bf16<<<DD / 8 / 256, 256, 0, stream>>>(q_w, wqb, DD / 8);
    cast_f32_bf16<<<DD / 8 / 256, 256, 0, stream>>>(k_w, wkb, DD / 8);
    cast_f32_bf16<<<DD / 8 / 256, 256, 0, stream>>>(conv_w, wcb, DD / 8);

    dim3 gg(B_ * N_ / 128, D_ / 128, 3);  // (25, 8, 3)
    mfma_gemm_nt<<<gg, 256, 0, stream>>>(featb, wqb, wkb, wcb, q_b, k_b,
                                         qb16, kb16, fk16);

    fkt_kernel<<<B_ * G_, 256, 0, stream>>>(fk16, fkT16);

    pos_fc1_kernel<<<B_ * N_, 256, 0, stream>>>(bbox, fc1_w, fc1_b,
                                                (const unsigned char*)maskp,
                                                (const int*)maskp, flag, wm);

    attn_mfma<<<B_ * G_, 256, 0, stream>>>(qb16, kb16, fkT16, wm,
                                           feat, conv_b, (float*)d_out);
}

// Round 6
// 129.136 us; speedup vs baseline: 4.6456x; 1.1214x over previous
//
#include <hip/hip_runtime.h>
#include <math.h>

#define B_  32
#define N_  100
#define G_  32
#define D_  1024
#define DG_ 32
#define FD_ 64

typedef __attribute__((ext_vector_type(8))) short short8;
typedef __attribute__((ext_vector_type(8))) unsigned short ushort8;
typedef __attribute__((ext_vector_type(4))) unsigned short ushort4v;
typedef __attribute__((ext_vector_type(4))) float f32x4;

__device__ inline unsigned short f2bf(float f) {
    unsigned int x = __float_as_uint(f);
    unsigned int r = (x + 0x7fffu + ((x >> 16) & 1u)) >> 16;  // RNE
    return (unsigned short)r;
}
__device__ inline unsigned short f2h(float f) {
    _Float16 h = (_Float16)f;
    return __builtin_bit_cast(unsigned short, h);
}
__device__ inline float h2f(unsigned short u) {
    return (float)__builtin_bit_cast(_Float16, u);
}
__device__ inline void load_lds16(const void* g, void* l) {
    __builtin_amdgcn_global_load_lds(
        (const __attribute__((address_space(1))) void*)g,
        (__attribute__((address_space(3))) void*)l, 16, 0, 0);
}

// ---------------------------------------------------------------------------
// Mask dtype detection (bool-byte vs int32).
// ---------------------------------------------------------------------------
__global__ __launch_bounds__(256) void detect_mask_kernel(
    const unsigned int* __restrict__ m, int nwords, int* __restrict__ flag)
{
    int v = 0;
    for (int i = blockIdx.x * 256 + threadIdx.x; i < nwords; i += gridDim.x * 256)
        v |= (m[i] > 1u) ? 1 : 0;
    if (__any(v) && (threadIdx.x & 63) == 0)
        atomicOr(flag, 1);
}

// ---------------------------------------------------------------------------
// Per-box precompute: cx, cy, log(bw), log(bh), 1/bw, 1/bh  (8 floats/box).
// ---------------------------------------------------------------------------
__global__ __launch_bounds__(256) void bbox_prep_kernel(
    const float* __restrict__ bbox, float* __restrict__ prep)
{
    const int i = blockIdx.x * 256 + threadIdx.x;
    if (i >= B_ * N_) return;
    const float4 bb = *reinterpret_cast<const float4*>(bbox + (size_t)i * 4);
    const float bw = bb.z - bb.x + 1.0f, bh = bb.w - bb.y + 1.0f;
    float4 o0, o1;
    o0.x = 0.5f * (bb.x + bb.z);
    o0.y = 0.5f * (bb.y + bb.w);
    o0.z = __logf(bw);
    o0.w = __logf(bh);
    o1.x = 1.0f / bw;
    o1.y = 1.0f / bh;
    o1.z = 0.0f; o1.w = 0.0f;
    *reinterpret_cast<float4*>(prep + (size_t)i * 8)     = o0;
    *reinterpret_cast<float4*>(prep + (size_t)i * 8 + 4) = o1;
}

// ---------------------------------------------------------------------------
// f32 -> bf16 cast, 8 elems/thread.
// ---------------------------------------------------------------------------
__global__ __launch_bounds__(256) void cast_f32_bf16(
    const float* __restrict__ src, unsigned short* __restrict__ dst, int n8)
{
    const int i = blockIdx.x * 256 + threadIdx.x;
    if (i >= n8) return;
    const float4 a = reinterpret_cast<const float4*>(src)[i * 2 + 0];
    const float4 b = reinterpret_cast<const float4*>(src)[i * 2 + 1];
    ushort8 o;
    o[0] = f2bf(a.x); o[1] = f2bf(a.y); o[2] = f2bf(a.z); o[3] = f2bf(a.w);
    o[4] = f2bf(b.x); o[5] = f2bf(b.y); o[6] = f2bf(b.z); o[7] = f2bf(b.w);
    *reinterpret_cast<ushort8*>(&dst[i * 8]) = o;
}

// ---------------------------------------------------------------------------
// bf16 MFMA GEMM NT. z=0: q(+q_b). z=1: k(+k_b). z=2: fk (no bias).
// ---------------------------------------------------------------------------
__global__ __launch_bounds__(256) void mfma_gemm_nt(
    const unsigned short* __restrict__ A,
    const unsigned short* __restrict__ Wq,
    const unsigned short* __restrict__ Wk,
    const unsigned short* __restrict__ Wc,
    const float* __restrict__ bq, const float* __restrict__ bk,
    unsigned short* __restrict__ Q16, unsigned short* __restrict__ K16,
    unsigned short* __restrict__ F16)
{
    __shared__ short As[128 * 64];
    __shared__ short Bs[128 * 64];

    const int z = blockIdx.z;
    const unsigned short* W = (z == 0) ? Wq : (z == 1) ? Wk : Wc;
    const float* bias        = (z == 0) ? bq : (z == 1) ? bk : nullptr;
    unsigned short* O        = (z == 0) ? Q16 : (z == 1) ? K16 : F16;

    const int m0 = blockIdx.x * 128;
    const int n0 = blockIdx.y * 128;
    const int t = threadIdx.x;
    const int lane = t & 63;
    const int wid = t >> 6;
    const int wr = wid >> 1, wc = wid & 1;

    f32x4 acc[4][4] = {};

    for (int k0 = 0; k0 < D_; k0 += 64) {
#pragma unroll
        for (int c = 0; c < 4; ++c) {
            const int idx16 = c * 256 + t;
            const int row = idx16 >> 3;
            const int colb = ((idx16 & 7) * 16) ^ ((row & 7) << 4);
            const char* ga = (const char*)(A + (size_t)(m0 + row) * D_ + k0) + colb;
            const char* gw = (const char*)(W + (size_t)(n0 + row) * D_ + k0) + colb;
            char* la = (char*)As + (c * 256 + wid * 64) * 16;
            char* lb = (char*)Bs + (c * 256 + wid * 64) * 16;
            load_lds16(ga, la);
            load_lds16(gw, lb);
        }
        __syncthreads();

#pragma unroll
        for (int ks = 0; ks < 2; ++ks) {
            short8 afr[4], bfr[4];
            const int kb = ks * 64 + (lane >> 4) * 16;
#pragma unroll
            for (int f = 0; f < 4; ++f) {
                const int am = wr * 64 + f * 16 + (lane & 15);
                afr[f] = *reinterpret_cast<const short8*>(
                    (const char*)As + am * 128 + (kb ^ ((am & 7) << 4)));
                const int bn = wc * 64 + f * 16 + (lane & 15);
                bfr[f] = *reinterpret_cast<const short8*>(
                    (const char*)Bs + bn * 128 + (kb ^ ((bn & 7) << 4)));
            }
#pragma unroll
            for (int i = 0; i < 4; ++i)
#pragma unroll
                for (int j = 0; j < 4; ++j)
                    acc[i][j] = __builtin_amdgcn_mfma_f32_16x16x32_bf16(
                        afr[i], bfr[j], acc[i][j], 0, 0, 0);
        }
        __syncthreads();
    }

#pragma unroll
    for (int j = 0; j < 4; ++j) {
        const int col = n0 + wc * 64 + j * 16 + (lane & 15);
        const float bv = bias ? bias[col] : 0.0f;
#pragma unroll
        for (int i = 0; i < 4; ++i) {
            const int mbase = m0 + wr * 64 + i * 16 + (lane >> 4) * 4;
#pragma unroll
            for (int r = 0; r < 4; ++r)
                O[(size_t)(mbase + r) * D_ + col] = f2bf(acc[i][j][r] + bv);
        }
    }
}

// ---------------------------------------------------------------------------
// fkT: fk16 (B*N,1024) bf16 -> fkT[(b*32+g)*32+dg][128] bf16, granules
// pre-swizzled by ^(dg&7). One block per (b,g).
// ---------------------------------------------------------------------------
__global__ __launch_bounds__(256) void fkt_kernel(
    const unsigned short* __restrict__ fk16, unsigned short* __restrict__ fkT)
{
    __shared__ unsigned short tile[DG_][N_ + 4];
    const int bg = blockIdx.x;
    const int b = bg >> 5, g = bg & 31;
    const int t = threadIdx.x;

    for (int i = t; i < N_ * 4; i += 256) {
        const int n = i >> 2, dg0 = (i & 3) * 8;
        const ushort8 v = *reinterpret_cast<const ushort8*>(
            fk16 + (size_t)(b * N_ + n) * D_ + g * DG_ + dg0);
#pragma unroll
        for (int j = 0; j < 8; ++j) tile[dg0 + j][n] = v[j];
    }
    __syncthreads();

    for (int u = t; u < DG_ * 16; u += 256) {
        const int dg = u >> 4, seg = u & 15;
        ushort8 o;
#pragma unroll
        for (int j = 0; j < 8; ++j) {
            const int n = seg * 8 + j;
            o[j] = (n < N_) ? tile[dg][n] : (unsigned short)0;
        }
        *reinterpret_cast<ushort8*>(
            fkT + ((size_t)bg * DG_ + dg) * 128 + (seg ^ (dg & 7)) * 8) = o;
    }
}

// ---------------------------------------------------------------------------
// pos_fc1: pairwise pos (hoisted, division-free) + f16 emb + fc1 MFMA +
// relu/log + mask fusion -> wm[b][g][q][128] f16 (granule-swizzled ^(q&7)).
// One block per (b,q), 4 waves.
// ---------------------------------------------------------------------------
__global__ __launch_bounds__(256) void pos_fc1_kernel(
    const float* __restrict__ prep, const float* __restrict__ fc1_w,
    const float* __restrict__ fc1_b,
    const unsigned char* __restrict__ mask8, const int* __restrict__ mask32,
    const int* __restrict__ flag, unsigned short* __restrict__ wm)
{
    __shared__ unsigned short embh[112 * 72];   // [k][f] f16, pad 72
    __shared__ unsigned short w1h[G_ * 72];
    __shared__ float b1[G_];
    __shared__ float tbl[8];
    __shared__ float pos4[N_][4];

    const int b = blockIdx.x / N_;
    const int q = blockIdx.x % N_;
    const int t = threadIdx.x;
    const int lane = t & 63;
    const int w = t >> 6;
    const int lo = lane & 15, hi = lane >> 4;

    // per-q constants (broadcast load)
    const float4 pq0 = *reinterpret_cast<const float4*>(prep + (size_t)(b * N_ + q) * 8);
    const float4 pq1 = *reinterpret_cast<const float4*>(prep + (size_t)(b * N_ + q) * 8 + 4);
    const float cxq = pq0.x, cyq = pq0.y, lbwq = pq0.z, lbhq = pq0.w;
    const float rbwq = pq1.x, rbhq = pq1.y;

    for (int i = t; i < G_ * FD_; i += 256)
        w1h[(i >> 6) * 72 + (i & 63)] = f2h(fc1_w[i]);
    if (t < G_) b1[t] = fc1_b[t];
    if (t < 8)  tbl[t] = 100.0f / powf(1000.0f, (float)t * 0.125f);
    for (int i = t; i < 12 * 64; i += 256)      // zero emb rows 100..111
        embh[(100 + (i >> 6)) * 72 + (i & 63)] = 0;

    // A0: per-k pos values, once per pair
    if (t < N_) {
        const float4 p0 = *reinterpret_cast<const float4*>(prep + (size_t)(b * N_ + t) * 8);
        pos4[t][0] = __logf(fmaxf(fabsf(cxq - p0.x) * rbwq, 1e-3f));
        pos4[t][1] = __logf(fmaxf(fabsf(cyq - p0.y) * rbhq, 1e-3f));
        pos4[t][2] = lbwq - p0.z;
        pos4[t][3] = lbhq - p0.w;
    }
    __syncthreads();

    // A1: trig only
    for (int idx = t; idx < N_ * 32; idx += 256) {
        const int k = idx >> 5;
        const int p = (idx >> 3) & 3;
        const int j = idx & 7;
        const float dv = pos4[k][p] * tbl[j];
        embh[k * 72 + p * 16 + j]     = f2h(__sinf(dv));
        embh[k * 72 + p * 16 + 8 + j] = f2h(__cosf(dv));
    }
    __syncthreads();

    // Phase B: 112(k) x 32(g) fc1 matmul via f16 MFMA + mask fuse + wm write
    const bool bytemask = (*flag != 0);
    const int xq = q & 7;
    for (int tid = w; tid < 14; tid += 4) {
        const int mt = tid >> 1, nt = tid & 1;
        f32x4 d = {};
#pragma unroll
        for (int ks = 0; ks < 2; ++ks) {
            const short8 af = *reinterpret_cast<const short8*>(
                embh + (mt * 16 + lo) * 72 + ks * 32 + hi * 8);
            const short8 bf = *reinterpret_cast<const short8*>(
                w1h + (nt * 16 + lo) * 72 + ks * 32 + hi * 8);
            d = __builtin_amdgcn_mfma_f32_16x16x32_f16(af, bf, d, 0, 0, 0);
        }
        const int g = nt * 16 + lo;
        const int k0 = mt * 16 + hi * 4;
        const float bb = b1[g];
        unsigned int mby = 0;
        uint4 mi = {};
        if (k0 < N_) {
            const size_t midx = ((size_t)(b * N_ + q) * G_ + g) * N_ + k0;
            if (bytemask) mby = *(const unsigned int*)(mask8 + midx);
            else          mi  = *(const uint4*)(mask32 + midx);
        }
        ushort4v ov;
#pragma unroll
        for (int r = 0; r < 4; ++r) {
            const int k = k0 + r;
            const bool msk = bytemask
                ? (((mby >> (8 * r)) & 0xffu) != 0u)
                : ((r == 0 ? mi.x : r == 1 ? mi.y : r == 2 ? mi.z : mi.w) != 0u);
            const float aff = d[r] + bb;
            const float lv = __logf(fmaxf(fmaxf(aff, 0.0f), 1e-6f));
            ov[r] = f2h((k >= N_ || msk) ? -65504.0f : lv);
        }
        const size_t row = (size_t)(b * G_ + g) * N_ + q;
        char* dst = (char*)wm + row * 256 + ((2 * k0) ^ (xq << 4));
        *reinterpret_cast<ushort4v*>(dst) = ov;
    }
}

// ---------------------------------------------------------------------------
// MFMA attention: one block per (b,g), 4 waves, one barrier.
// ---------------------------------------------------------------------------
__global__ __launch_bounds__(256) void attn_mfma(
    const unsigned short* __restrict__ qb, const unsigned short* __restrict__ kb,
    const unsigned short* __restrict__ fkT, const unsigned short* __restrict__ wm,
    const float* __restrict__ feat, const float* __restrict__ conv_b,
    float* __restrict__ out)
{
    __shared__ unsigned short PW[128 * 128];   // 32KB
    __shared__ unsigned short FL[DG_ * 128];   // 8KB

    const int bg = blockIdx.x;
    const int b = bg >> 5, g = bg & 31;
    const int t = threadIdx.x;
    const int lane = t & 63;
    const int w = t >> 6;
    const int lo = lane & 15, hi = lane >> 4;
    const float scale = 0.17677669529663687f;  // 1/sqrt(32)

    // ---- stage wmask (1600 x 16B) and fkT (512 x 16B), both linear ----
    {
        const char* src = (const char*)(wm + (size_t)bg * N_ * 128);
        for (int u = t; u < 1600; u += 256)
            load_lds16(src + u * 16, (char*)PW + u * 16);
        const char* fsrc = (const char*)(fkT + (size_t)bg * DG_ * 128);
        for (int u = t; u < 512; u += 256)
            load_lds16(fsrc + u * 16, (char*)FL + u * 16);
    }

    // ---- Q/K fragments direct from global bf16 ----
    short8 qf[2], kf[7];
#pragma unroll
    for (int mtl = 0; mtl < 2; ++mtl) {
        const int row = w * 32 + mtl * 16 + lo;
        const int rc = row < N_ ? row : N_ - 1;
        qf[mtl] = *reinterpret_cast<const short8*>(
            qb + (size_t)(b * N_ + rc) * D_ + g * DG_ + hi * 8);
    }
#pragma unroll
    for (int ct = 0; ct < 7; ++ct) {
        const int kr = ct * 16 + lo;
        const int krc = kr < N_ ? kr : N_ - 1;
        kf[ct] = *reinterpret_cast<const short8*>(
            kb + (size_t)(b * N_ + krc) * D_ + g * DG_ + hi * 8);
    }

    __syncthreads();   // staging complete

    // ---- QK^T ----
    f32x4 s[2][7];
#pragma unroll
    for (int mtl = 0; mtl < 2; ++mtl)
#pragma unroll
        for (int ct = 0; ct < 7; ++ct) {
            f32x4 z = {};
            s[mtl][ct] = __builtin_amdgcn_mfma_f32_16x16x32_bf16(
                qf[mtl], kf[ct], z, 0, 0, 0);
        }

    // ---- scale + wmask ----
#pragma unroll
    for (int mtl = 0; mtl < 2; ++mtl) {
        const int qr0 = w * 32 + mtl * 16 + hi * 4;
#pragma unroll
        for (int ct = 0; ct < 7; ++ct) {
            const int k = ct * 16 + lo;
#pragma unroll
            for (int r = 0; r < 4; ++r) {
                const int row = qr0 + r;
                const float wv = h2f(*(const unsigned short*)(
                    (const char*)PW + row * 256 + ((2 * k) ^ ((row & 7) << 4))));
                s[mtl][ct][r] = s[mtl][ct][r] * scale + wv;
            }
        }
    }

    // ---- in-register row softmax ----
    float sm[2][4];
#pragma unroll
    for (int mtl = 0; mtl < 2; ++mtl) {
        f32x4 mv = s[mtl][0];
#pragma unroll
        for (int ct = 1; ct < 7; ++ct)
#pragma unroll
            for (int r = 0; r < 4; ++r) mv[r] = fmaxf(mv[r], s[mtl][ct][r]);
        float mx[4];
#pragma unroll
        for (int r = 0; r < 4; ++r) {
            float m = mv[r];
            m = fmaxf(m, __shfl_xor(m, 1));
            m = fmaxf(m, __shfl_xor(m, 2));
            m = fmaxf(m, __shfl_xor(m, 4));
            m = fmaxf(m, __shfl_xor(m, 8));
            mx[r] = m;
        }
        f32x4 sv = {};
#pragma unroll
        for (int ct = 0; ct < 7; ++ct)
#pragma unroll
            for (int r = 0; r < 4; ++r) {
                const float e = __expf(s[mtl][ct][r] - mx[r]);
                s[mtl][ct][r] = e;
                sv[r] += e;
            }
#pragma unroll
        for (int r = 0; r < 4; ++r) {
            float ss = sv[r];
            ss += __shfl_xor(ss, 1);
            ss += __shfl_xor(ss, 2);
            ss += __shfl_xor(ss, 4);
            ss += __shfl_xor(ss, 8);
            sm[mtl][r] = 1.0f / ss;
        }
    }

    // ---- P -> bf16 -> PW in-place (wave-private rows) ----
#pragma unroll
    for (int mtl = 0; mtl < 2; ++mtl) {
        const int qr0 = w * 32 + mtl * 16 + hi * 4;
#pragma unroll
        for (int ct = 0; ct < 7; ++ct) {
            const int col = ct * 16 + lo;
#pragma unroll
            for (int r = 0; r < 4; ++r) {
                const int row = qr0 + r;
                *(unsigned short*)((char*)PW + row * 256 +
                                   ((2 * col) ^ ((row & 7) << 4))) =
                    f2bf(s[mtl][ct][r] * sm[mtl][r]);
            }
        }
    }
    // zero-fill pad granules 14,15 of this wave's 32 rows
    {
        const int zr = w * 32 + (lane & 31);
        const int zg = 14 + (lane >> 5);
        short8 zs = {};
        *reinterpret_cast<short8*>(
            (char*)PW + zr * 256 + ((zg * 16) ^ ((zr & 7) << 4))) = zs;
    }

    // ---- PV ----
    f32x4 o[2][2] = {};
#pragma unroll
    for (int ks = 0; ks < 4; ++ks) {
        short8 pa[2], fb[2];
#pragma unroll
        for (int mtl = 0; mtl < 2; ++mtl) {
            const int prow = w * 32 + mtl * 16 + lo;
            pa[mtl] = *reinterpret_cast<const short8*>(
                (const char*)PW + prow * 256 +
                ((ks * 64 + hi * 16) ^ ((prow & 7) << 4)));
        }
#pragma unroll
        for (int nt = 0; nt < 2; ++nt) {
            const int dg = nt * 16 + lo;
            fb[nt] = *reinterpret_cast<const short8*>(
                (const char*)FL + dg * 256 +
                ((ks * 64 + hi * 16) ^ ((dg & 7) << 4)));
        }
#pragma unroll
        for (int mtl = 0; mtl < 2; ++mtl)
#pragma unroll
            for (int nt = 0; nt < 2; ++nt)
                o[mtl][nt] = __builtin_amdgcn_mfma_f32_16x16x32_bf16(
                    pa[mtl], fb[nt], o[mtl][nt], 0, 0, 0);
    }

    // ---- epilogue ----
#pragma unroll
    for (int mtl = 0; mtl < 2; ++mtl) {
        const int qr0 = w * 32 + mtl * 16 + hi * 4;
#pragma unroll
        for (int nt = 0; nt < 2; ++nt) {
            const int col = g * DG_ + nt * 16 + lo;
            const float cb = conv_b[col];
#pragma unroll
            for (int r = 0; r < 4; ++r) {
                const int q = qr0 + r;
                if (q < N_) {
                    const size_t gi = (size_t)(b * N_ + q) * D_ + col;
                    out[gi] = fmaxf(feat[gi] + o[mtl][nt][r] + cb, 0.0f);
                }
            }
        }
    }
}

// ---------------------------------------------------------------------------
extern "C" void kernel_launch(void* const* d_in, const int* in_sizes, int n_in,
                              void* d_out, int out_size, void* d_ws, size_t ws_size,
                              hipStream_t stream)
{
    const float* feat   = (const float*)d_in[0];
    const float* bbox   = (const float*)d_in[1];
    const void*  maskp  = d_in[2];
    const float* fc1_w  = (const float*)d_in[3];
    const float* fc1_b  = (const float*)d_in[4];
    const float* q_w    = (const float*)d_in[5];
    const float* q_b    = (const float*)d_in[6];
    const float* k_w    = (const float*)d_in[7];
    const float* k_b    = (const float*)d_in[8];
    const float* conv_w = (const float*)d_in[9];
    const float* conv_b = (const float*)d_in[10];

    const int BN_D  = B_ * N_ * D_;          // 3,276,800
    const int BNGN  = B_ * N_ * G_ * N_;     // 10,240,000
    const int DD    = D_ * D_;               // 1,048,576
    const int FKT_N = B_ * G_ * DG_ * 128;   // 4,194,304
    const int WM_N  = B_ * G_ * N_ * 128;    // 13,107,200

    unsigned short* ws16 = (unsigned short*)d_ws;
    unsigned short* qb16  = ws16;
    unsigned short* kb16  = qb16 + BN_D;
    unsigned short* fk16  = kb16 + BN_D;
    unsigned short* fkT16 = fk16 + BN_D;
    unsigned short* wm    = fkT16 + FKT_N;
    int* flag = (int*)(wm + WM_N);
    float* prep = (float*)(flag + 64);       // 3200*8 floats

    // bf16 cast staging aliases wm (dead before pos_fc1 writes wm)
    unsigned short* featb = wm;
    unsigned short* wqb   = featb + BN_D;
    unsigned short* wkb   = wqb + DD;
    unsigned short* wcb   = wkb + DD;

    hipMemsetAsync(flag, 0, sizeof(int), stream);
    detect_mask_kernel<<<256, 256, 0, stream>>>((const unsigned int*)maskp,
                                                BNGN / 4, flag);

    bbox_prep_kernel<<<(B_ * N_ + 255) / 256, 256, 0, stream>>>(bbox, prep);

    cast_f32_bf16<<<BN_D / 8 / 256, 256, 0, stream>>>(feat, featb, BN_D / 8);
    cast_f32_bf16<<<DD / 8 / 256, 256, 0, stream>>>(q_w, wqb, DD / 8);
    cast_f32_bf16<<<DD / 8 / 256, 256, 0, stream>>>(k_w, wkb, DD / 8);
    cast_f32_bf16<<<DD / 8 / 256, 256, 0, stream>>>(conv_w, wcb, DD / 8);

    dim3 gg(B_ * N_ / 128, D_ / 128, 3);  // (25, 8, 3)
    mfma_gemm_nt<<<gg, 256, 0, stream>>>(featb, wqb, wkb, wcb, q_b, k_b,
                                         qb16, kb16, fk16);

    fkt_kernel<<<B_ * G_, 256, 0, stream>>>(fk16, fkT16);

    pos_fc1_kernel<<<B_ * N_, 256, 0, stream>>>(prep, fc1_w, fc1_b,
                                                (const unsigned char*)maskp,
                                                (const int*)maskp, flag, wm);

    attn_mfma<<<B_ * G_, 256, 0, stream>>>(qb16, kb16, fkT16, wm,
                                           feat, conv_b, (float*)d_out);
}

// Round 7
// 103.838 us; speedup vs baseline: 5.7774x; 1.2436x over previous
//
#include <hip/hip_runtime.h>
#include <math.h>

#define B_  32
#define N_  100
#define G_  32
#define D_  1024
#define DG_ 32
#define FD_ 64

typedef __attribute__((ext_vector_type(8))) short short8;
typedef __attribute__((ext_vector_type(8))) unsigned short ushort8;
typedef __attribute__((ext_vector_type(4))) unsigned short ushort4v;
typedef __attribute__((ext_vector_type(4))) float f32x4;

__device__ inline unsigned short f2bf(float f) {
    unsigned int x = __float_as_uint(f);
    unsigned int r = (x + 0x7fffu + ((x >> 16) & 1u)) >> 16;  // RNE
    return (unsigned short)r;
}
__device__ inline unsigned short f2h(float f) {
    _Float16 h = (_Float16)f;
    return __builtin_bit_cast(unsigned short, h);
}
__device__ inline float h2f(unsigned short u) {
    return (float)__builtin_bit_cast(_Float16, u);
}
__device__ inline void load_lds16(const void* g, void* l) {
    __builtin_amdgcn_global_load_lds(
        (const __attribute__((address_space(1))) void*)g,
        (__attribute__((address_space(3))) void*)l, 16, 0, 0);
}

// ---------------------------------------------------------------------------
// Fused prep: [0,256) mask detect | [256,272) bbox prep | [272,1872) feat cast
// | [1872,2384) q_w cast | [2384,2896) k_w cast | [2896,3408) conv_w cast.
// ---------------------------------------------------------------------------
__global__ __launch_bounds__(256) void prep_kernel(
    const unsigned int* __restrict__ mask, int* __restrict__ flag,
    const float* __restrict__ bbox, float* __restrict__ prep,
    const float* __restrict__ feat, unsigned short* __restrict__ featb,
    const float* __restrict__ qw, unsigned short* __restrict__ wqb,
    const float* __restrict__ kw, unsigned short* __restrict__ wkb,
    const float* __restrict__ cw, unsigned short* __restrict__ wcb)
{
    const int bid = blockIdx.x;
    const int t = threadIdx.x;
    if (bid < 256) {
        const int nwords = (B_ * N_ * G_ * N_) / 4;
        int v = 0;
        for (int i = bid * 256 + t; i < nwords; i += 256 * 256)
            v |= (mask[i] > 1u) ? 1 : 0;
        if (__any(v) && (t & 63) == 0) atomicOr(flag, 1);
        return;
    }
    if (bid < 272) {
        const int i = (bid - 256) * 256 + t;
        if (i < B_ * N_) {
            const float4 bb = *reinterpret_cast<const float4*>(bbox + (size_t)i * 4);
            const float bw = bb.z - bb.x + 1.0f, bh = bb.w - bb.y + 1.0f;
            float4 o0, o1;
            o0.x = 0.5f * (bb.x + bb.z);
            o0.y = 0.5f * (bb.y + bb.w);
            o0.z = __logf(bw);
            o0.w = __logf(bh);
            o1.x = 1.0f / bw;
            o1.y = 1.0f / bh;
            o1.z = 0.0f; o1.w = 0.0f;
            *reinterpret_cast<float4*>(prep + (size_t)i * 8)     = o0;
            *reinterpret_cast<float4*>(prep + (size_t)i * 8 + 4) = o1;
        }
        return;
    }
    const float* src;
    unsigned short* dst;
    int i;
    if (bid < 1872)      { src = feat; dst = featb; i = (bid - 272) * 256 + t; }
    else if (bid < 2384) { src = qw;   dst = wqb;   i = (bid - 1872) * 256 + t; }
    else if (bid < 2896) { src = kw;   dst = wkb;   i = (bid - 2384) * 256 + t; }
    else                 { src = cw;   dst = wcb;   i = (bid - 2896) * 256 + t; }
    const float4 a = reinterpret_cast<const float4*>(src)[i * 2 + 0];
    const float4 b = reinterpret_cast<const float4*>(src)[i * 2 + 1];
    ushort8 o;
    o[0] = f2bf(a.x); o[1] = f2bf(a.y); o[2] = f2bf(a.z); o[3] = f2bf(a.w);
    o[4] = f2bf(b.x); o[5] = f2bf(b.y); o[6] = f2bf(b.z); o[7] = f2bf(b.w);
    *reinterpret_cast<ushort8*>(&dst[i * 8]) = o;
}

// ---------------------------------------------------------------------------
// bf16 MFMA GEMM NT, 128x64 tile, BK=64, double-buffered LDS (T3 2-phase).
// z=0: q(+q_b). z=1: k(+k_b). z=2: fk (no bias). All outputs bf16.
// ---------------------------------------------------------------------------
__global__ __launch_bounds__(256) void mfma_gemm_nt(
    const unsigned short* __restrict__ A,
    const unsigned short* __restrict__ Wq,
    const unsigned short* __restrict__ Wk,
    const unsigned short* __restrict__ Wc,
    const float* __restrict__ bq, const float* __restrict__ bk,
    unsigned short* __restrict__ Q16, unsigned short* __restrict__ K16,
    unsigned short* __restrict__ F16)
{
    __shared__ short As0[128 * 64], As1[128 * 64];   // 16 KB each
    __shared__ short Bs0[64 * 64],  Bs1[64 * 64];    // 8 KB each

    const int z = blockIdx.z;
    const unsigned short* W = (z == 0) ? Wq : (z == 1) ? Wk : Wc;
    const float* bias        = (z == 0) ? bq : (z == 1) ? bk : nullptr;
    unsigned short* O        = (z == 0) ? Q16 : (z == 1) ? K16 : F16;

    const int m0 = blockIdx.x * 128;
    const int n0 = blockIdx.y * 64;
    const int t = threadIdx.x;
    const int lane = t & 63;
    const int wid = t >> 6;
    const int wr = wid >> 1, wc = wid & 1;
    const int lo = lane & 15, hi = lane >> 4;

    f32x4 acc[4][2] = {};

    // stage one K-tile (A: 1024 granules, B: 512 granules)
    auto STAGE = [&](short* dA, short* dB, int k0) {
#pragma unroll
        for (int c = 0; c < 4; ++c) {
            const int idx16 = c * 256 + t;
            const int row = idx16 >> 3;
            const int colb = ((idx16 & 7) * 16) ^ ((row & 7) << 4);
            load_lds16((const char*)(A + (size_t)(m0 + row) * D_ + k0) + colb,
                       (char*)dA + (c * 256 + wid * 64) * 16);
        }
#pragma unroll
        for (int c = 0; c < 2; ++c) {
            const int idx16 = c * 256 + t;
            const int row = idx16 >> 3;
            const int colb = ((idx16 & 7) * 16) ^ ((row & 7) << 4);
            load_lds16((const char*)(W + (size_t)(n0 + row) * D_ + k0) + colb,
                       (char*)dB + (c * 256 + wid * 64) * 16);
        }
    };

    auto COMPUTE = [&](const short* sA, const short* sB) {
#pragma unroll
        for (int ks = 0; ks < 2; ++ks) {
            short8 afr[4], bfr[2];
            const int kb = ks * 64 + hi * 16;
#pragma unroll
            for (int f = 0; f < 4; ++f) {
                const int am = wr * 64 + f * 16 + lo;
                afr[f] = *reinterpret_cast<const short8*>(
                    (const char*)sA + am * 128 + (kb ^ ((am & 7) << 4)));
            }
#pragma unroll
            for (int j = 0; j < 2; ++j) {
                const int bn = wc * 32 + j * 16 + lo;
                bfr[j] = *reinterpret_cast<const short8*>(
                    (const char*)sB + bn * 128 + (kb ^ ((bn & 7) << 4)));
            }
#pragma unroll
            for (int i = 0; i < 4; ++i)
#pragma unroll
                for (int j = 0; j < 2; ++j)
                    acc[i][j] = __builtin_amdgcn_mfma_f32_16x16x32_bf16(
                        afr[i], bfr[j], acc[i][j], 0, 0, 0);
        }
    };

    STAGE(As0, Bs0, 0);
    __syncthreads();
    for (int it = 0; it < 16; it += 2) {
        STAGE(As1, Bs1, (it + 1) << 6);     // issue next-tile loads early
        COMPUTE(As0, Bs0);
        __syncthreads();                    // drains vmcnt: As1/Bs1 ready
        if (it + 2 < 16) STAGE(As0, Bs0, (it + 2) << 6);
        COMPUTE(As1, Bs1);
        __syncthreads();
    }

#pragma unroll
    for (int j = 0; j < 2; ++j) {
        const int col = n0 + wc * 32 + j * 16 + lo;
        const float bv = bias ? bias[col] : 0.0f;
#pragma unroll
        for (int i = 0; i < 4; ++i) {
            const int mbase = m0 + wr * 64 + i * 16 + hi * 4;
#pragma unroll
            for (int r = 0; r < 4; ++r)
                O[(size_t)(mbase + r) * D_ + col] = f2bf(acc[i][j][r] + bv);
        }
    }
}

// ---------------------------------------------------------------------------
// fkT: fk16 (B*N,1024) bf16 -> fkT[(b*32+g)*32+dg][128] bf16, granules
// pre-swizzled by ^(dg&7). One block per (b,g).
// ---------------------------------------------------------------------------
__global__ __launch_bounds__(256) void fkt_kernel(
    const unsigned short* __restrict__ fk16, unsigned short* __restrict__ fkT)
{
    __shared__ unsigned short tile[DG_][N_ + 4];
    const int bg = blockIdx.x;
    const int b = bg >> 5, g = bg & 31;
    const int t = threadIdx.x;

    for (int i = t; i < N_ * 4; i += 256) {
        const int n = i >> 2, dg0 = (i & 3) * 8;
        const ushort8 v = *reinterpret_cast<const ushort8*>(
            fk16 + (size_t)(b * N_ + n) * D_ + g * DG_ + dg0);
#pragma unroll
        for (int j = 0; j < 8; ++j) tile[dg0 + j][n] = v[j];
    }
    __syncthreads();

    for (int u = t; u < DG_ * 16; u += 256) {
        const int dg = u >> 4, seg = u & 15;
        ushort8 o;
#pragma unroll
        for (int j = 0; j < 8; ++j) {
            const int n = seg * 8 + j;
            o[j] = (n < N_) ? tile[dg][n] : (unsigned short)0;
        }
        *reinterpret_cast<ushort8*>(
            fkT + ((size_t)bg * DG_ + dg) * 128 + (seg ^ (dg & 7)) * 8) = o;
    }
}

// ---------------------------------------------------------------------------
// pos_fc1: pairwise pos (hoisted, division-free) + f16 emb + fc1 MFMA +
// relu/log + mask fusion -> wm[b][g][q][128] f16 (granule-swizzled ^(q&7)).
// One block per (b,q), 4 waves.
// ---------------------------------------------------------------------------
__global__ __launch_bounds__(256) void pos_fc1_kernel(
    const float* __restrict__ prep, const float* __restrict__ fc1_w,
    const float* __restrict__ fc1_b,
    const unsigned char* __restrict__ mask8, const int* __restrict__ mask32,
    const int* __restrict__ flag, unsigned short* __restrict__ wm)
{
    __shared__ unsigned short embh[112 * 72];   // [k][f] f16, pad 72
    __shared__ unsigned short w1h[G_ * 72];
    __shared__ float b1[G_];
    __shared__ float tbl[8];
    __shared__ float pos4[N_][4];

    const int b = blockIdx.x / N_;
    const int q = blockIdx.x % N_;
    const int t = threadIdx.x;
    const int lane = t & 63;
    const int w = t >> 6;
    const int lo = lane & 15, hi = lane >> 4;

    const float4 pq0 = *reinterpret_cast<const float4*>(prep + (size_t)(b * N_ + q) * 8);
    const float4 pq1 = *reinterpret_cast<const float4*>(prep + (size_t)(b * N_ + q) * 8 + 4);
    const float cxq = pq0.x, cyq = pq0.y, lbwq = pq0.z, lbhq = pq0.w;
    const float rbwq = pq1.x, rbhq = pq1.y;

    for (int i = t; i < G_ * FD_; i += 256)
        w1h[(i >> 6) * 72 + (i & 63)] = f2h(fc1_w[i]);
    if (t < G_) b1[t] = fc1_b[t];
    if (t < 8)  tbl[t] = 100.0f / powf(1000.0f, (float)t * 0.125f);
    for (int i = t; i < 12 * 64; i += 256)
        embh[(100 + (i >> 6)) * 72 + (i & 63)] = 0;

    if (t < N_) {
        const float4 p0 = *reinterpret_cast<const float4*>(prep + (size_t)(b * N_ + t) * 8);
        pos4[t][0] = __logf(fmaxf(fabsf(cxq - p0.x) * rbwq, 1e-3f));
        pos4[t][1] = __logf(fmaxf(fabsf(cyq - p0.y) * rbhq, 1e-3f));
        pos4[t][2] = lbwq - p0.z;
        pos4[t][3] = lbhq - p0.w;
    }
    __syncthreads();

    for (int idx = t; idx < N_ * 32; idx += 256) {
        const int k = idx >> 5;
        const int p = (idx >> 3) & 3;
        const int j = idx & 7;
        const float dv = pos4[k][p] * tbl[j];
        embh[k * 72 + p * 16 + j]     = f2h(__sinf(dv));
        embh[k * 72 + p * 16 + 8 + j] = f2h(__cosf(dv));
    }
    __syncthreads();

    const bool bytemask = (*flag != 0);
    const int xq = q & 7;
    for (int tid = w; tid < 14; tid += 4) {
        const int mt = tid >> 1, nt = tid & 1;
        f32x4 d = {};
#pragma unroll
        for (int ks = 0; ks < 2; ++ks) {
            const short8 af = *reinterpret_cast<const short8*>(
                embh + (mt * 16 + lo) * 72 + ks * 32 + hi * 8);
            const short8 bf = *reinterpret_cast<const short8*>(
                w1h + (nt * 16 + lo) * 72 + ks * 32 + hi * 8);
            d = __builtin_amdgcn_mfma_f32_16x16x32_f16(af, bf, d, 0, 0, 0);
        }
        const int g = nt * 16 + lo;
        const int k0 = mt * 16 + hi * 4;
        const float bb = b1[g];
        unsigned int mby = 0;
        uint4 mi = {};
        if (k0 < N_) {
            const size_t midx = ((size_t)(b * N_ + q) * G_ + g) * N_ + k0;
            if (bytemask) mby = *(const unsigned int*)(mask8 + midx);
            else          mi  = *(const uint4*)(mask32 + midx);
        }
        ushort4v ov;
#pragma unroll
        for (int r = 0; r < 4; ++r) {
            const int k = k0 + r;
            const bool msk = bytemask
                ? (((mby >> (8 * r)) & 0xffu) != 0u)
                : ((r == 0 ? mi.x : r == 1 ? mi.y : r == 2 ? mi.z : mi.w) != 0u);
            const float aff = d[r] + bb;
            const float lv = __logf(fmaxf(fmaxf(aff, 0.0f), 1e-6f));
            ov[r] = f2h((k >= N_ || msk) ? -65504.0f : lv);
        }
        const size_t row = (size_t)(b * G_ + g) * N_ + q;
        char* dst = (char*)wm + row * 256 + ((2 * k0) ^ (xq << 4));
        *reinterpret_cast<ushort4v*>(dst) = ov;
    }
}

// ---------------------------------------------------------------------------
// MFMA attention: one block per (b,g), 4 waves, one barrier.
// ---------------------------------------------------------------------------
__global__ __launch_bounds__(256) void attn_mfma(
    const unsigned short* __restrict__ qb, const unsigned short* __restrict__ kb,
    const unsigned short* __restrict__ fkT, const unsigned short* __restrict__ wm,
    const float* __restrict__ feat, const float* __restrict__ conv_b,
    float* __restrict__ out)
{
    __shared__ unsigned short PW[128 * 128];   // 32KB
    __shared__ unsigned short FL[DG_ * 128];   // 8KB

    const int bg = blockIdx.x;
    const int b = bg >> 5, g = bg & 31;
    const int t = threadIdx.x;
    const int lane = t & 63;
    const int w = t >> 6;
    const int lo = lane & 15, hi = lane >> 4;
    const float scale = 0.17677669529663687f;  // 1/sqrt(32)

    {
        const char* src = (const char*)(wm + (size_t)bg * N_ * 128);
        for (int u = t; u < 1600; u += 256)
            load_lds16(src + u * 16, (char*)PW + u * 16);
        const char* fsrc = (const char*)(fkT + (size_t)bg * DG_ * 128);
        for (int u = t; u < 512; u += 256)
            load_lds16(fsrc + u * 16, (char*)FL + u * 16);
    }

    short8 qf[2], kf[7];
#pragma unroll
    for (int mtl = 0; mtl < 2; ++mtl) {
        const int row = w * 32 + mtl * 16 + lo;
        const int rc = row < N_ ? row : N_ - 1;
        qf[mtl] = *reinterpret_cast<const short8*>(
            qb + (size_t)(b * N_ + rc) * D_ + g * DG_ + hi * 8);
    }
#pragma unroll
    for (int ct = 0; ct < 7; ++ct) {
        const int kr = ct * 16 + lo;
        const int krc = kr < N_ ? kr : N_ - 1;
        kf[ct] = *reinterpret_cast<const short8*>(
            kb + (size_t)(b * N_ + krc) * D_ + g * DG_ + hi * 8);
    }

    __syncthreads();

    f32x4 s[2][7];
#pragma unroll
    for (int mtl = 0; mtl < 2; ++mtl)
#pragma unroll
        for (int ct = 0; ct < 7; ++ct) {
            f32x4 z = {};
            s[mtl][ct] = __builtin_amdgcn_mfma_f32_16x16x32_bf16(
                qf[mtl], kf[ct], z, 0, 0, 0);
        }

#pragma unroll
    for (int mtl = 0; mtl < 2; ++mtl) {
        const int qr0 = w * 32 + mtl * 16 + hi * 4;
#pragma unroll
        for (int ct = 0; ct < 7; ++ct) {
            const int k = ct * 16 + lo;
#pragma unroll
            for (int r = 0; r < 4; ++r) {
                const int row = qr0 + r;
                const float wv = h2f(*(const unsigned short*)(
                    (const char*)PW + row * 256 + ((2 * k) ^ ((row & 7) << 4))));
                s[mtl][ct][r] = s[mtl][ct][r] * scale + wv;
            }
        }
    }

    float sm[2][4];
#pragma unroll
    for (int mtl = 0; mtl < 2; ++mtl) {
        f32x4 mv = s[mtl][0];
#pragma unroll
        for (int ct = 1; ct < 7; ++ct)
#pragma unroll
            for (int r = 0; r < 4; ++r) mv[r] = fmaxf(mv[r], s[mtl][ct][r]);
        float mx[4];
#pragma unroll
        for (int r = 0; r < 4; ++r) {
            float m = mv[r];
            m = fmaxf(m, __shfl_xor(m, 1));
            m = fmaxf(m, __shfl_xor(m, 2));
            m = fmaxf(m, __shfl_xor(m, 4));
            m = fmaxf(m, __shfl_xor(m, 8));
            mx[r] = m;
        }
        f32x4 sv = {};
#pragma unroll
        for (int ct = 0; ct < 7; ++ct)
#pragma unroll
            for (int r = 0; r < 4; ++r) {
                const float e = __expf(s[mtl][ct][r] - mx[r]);
                s[mtl][ct][r] = e;
                sv[r] += e;
            }
#pragma unroll
        for (int r = 0; r < 4; ++r) {
            float ss = sv[r];
            ss += __shfl_xor(ss, 1);
            ss += __shfl_xor(ss, 2);
            ss += __shfl_xor(ss, 4);
            ss += __shfl_xor(ss, 8);
            sm[mtl][r] = 1.0f / ss;
        }
    }

#pragma unroll
    for (int mtl = 0; mtl < 2; ++mtl) {
        const int qr0 = w * 32 + mtl * 16 + hi * 4;
#pragma unroll
        for (int ct = 0; ct < 7; ++ct) {
            const int col = ct * 16 + lo;
#pragma unroll
            for (int r = 0; r < 4; ++r) {
                const int row = qr0 + r;
                *(unsigned short*)((char*)PW + row * 256 +
                                   ((2 * col) ^ ((row & 7) << 4))) =
                    f2bf(s[mtl][ct][r] * sm[mtl][r]);
            }
        }
    }
    {
        const int zr = w * 32 + (lane & 31);
        const int zg = 14 + (lane >> 5);
        short8 zs = {};
        *reinterpret_cast<short8*>(
            (char*)PW + zr * 256 + ((zg * 16) ^ ((zr & 7) << 4))) = zs;
    }

    f32x4 o[2][2] = {};
#pragma unroll
    for (int ks = 0; ks < 4; ++ks) {
        short8 pa[2], fb[2];
#pragma unroll
        for (int mtl = 0; mtl < 2; ++mtl) {
            const int prow = w * 32 + mtl * 16 + lo;
            pa[mtl] = *reinterpret_cast<const short8*>(
                (const char*)PW + prow * 256 +
                ((ks * 64 + hi * 16) ^ ((prow & 7) << 4)));
        }
#pragma unroll
        for (int nt = 0; nt < 2; ++nt) {
            const int dg = nt * 16 + lo;
            fb[nt] = *reinterpret_cast<const short8*>(
                (const char*)FL + dg * 256 +
                ((ks * 64 + hi * 16) ^ ((dg & 7) << 4)));
        }
#pragma unroll
        for (int mtl = 0; mtl < 2; ++mtl)
#pragma unroll
            for (int nt = 0; nt < 2; ++nt)
                o[mtl][nt] = __builtin_amdgcn_mfma_f32_16x16x32_bf16(
                    pa[mtl], fb[nt], o[mtl][nt], 0, 0, 0);
    }

#pragma unroll
    for (int mtl = 0; mtl < 2; ++mtl) {
        const int qr0 = w * 32 + mtl * 16 + hi * 4;
#pragma unroll
        for (int nt = 0; nt < 2; ++nt) {
            const int col = g * DG_ + nt * 16 + lo;
            const float cb = conv_b[col];
#pragma unroll
            for (int r = 0; r < 4; ++r) {
                const int q = qr0 + r;
                if (q < N_) {
                    const size_t gi = (size_t)(b * N_ + q) * D_ + col;
                    out[gi] = fmaxf(feat[gi] + o[mtl][nt][r] + cb, 0.0f);
                }
            }
        }
    }
}

// ---------------------------------------------------------------------------
extern "C" void kernel_launch(void* const* d_in, const int* in_sizes, int n_in,
                              void* d_out, int out_size, void* d_ws, size_t ws_size,
                              hipStream_t stream)
{
    const float* feat   = (const float*)d_in[0];
    const float* bbox   = (const float*)d_in[1];
    const void*  maskp  = d_in[2];
    const float* fc1_w  = (const float*)d_in[3];
    const float* fc1_b  = (const float*)d_in[4];
    const float* q_w    = (const float*)d_in[5];
    const float* q_b    = (const float*)d_in[6];
    const float* k_w    = (const float*)d_in[7];
    const float* k_b    = (const float*)d_in[8];
    const float* conv_w = (const float*)d_in[9];
    const float* conv_b = (const float*)d_in[10];

    const int BN_D  = B_ * N_ * D_;          // 3,276,800
    const int BNGN  = B_ * N_ * G_ * N_;     // 10,240,000
    const int DD    = D_ * D_;               // 1,048,576
    const int FKT_N = B_ * G_ * DG_ * 128;   // 4,194,304
    const int WM_N  = B_ * G_ * N_ * 128;    // 13,107,200

    unsigned short* ws16 = (unsigned short*)d_ws;
    unsigned short* qb16  = ws16;
    unsigned short* kb16  = qb16 + BN_D;
    unsigned short* fk16  = kb16 + BN_D;
    unsigned short* fkT16 = fk16 + BN_D;
    unsigned short* wm    = fkT16 + FKT_N;
    int* flag = (int*)(wm + WM_N);
    float* prep = (float*)(flag + 64);       // 3200*8 floats

    // bf16 cast staging aliases wm (dead before pos_fc1 writes wm)
    unsigned short* featb = wm;
    unsigned short* wqb   = featb + BN_D;
    unsigned short* wkb   = wqb + DD;
    unsigned short* wcb   = wkb + DD;

    hipMemsetAsync(flag, 0, sizeof(int), stream);
    prep_kernel<<<3408, 256, 0, stream>>>((const unsigned int*)maskp, flag,
                                          bbox, prep, feat, featb,
                                          q_w, wqb, k_w, wkb, conv_w, wcb);

    dim3 gg(B_ * N_ / 128, D_ / 64, 3);  // (25, 16, 3)
    mfma_gemm_nt<<<gg, 256, 0, stream>>>(featb, wqb, wkb, wcb, q_b, k_b,
                                         qb16, kb16, fk16);

    fkt_kernel<<<B_ * G_, 256, 0, stream>>>(fk16, fkT16);

    pos_fc1_kernel<<<B_ * N_, 256, 0, stream>>>(prep, fc1_w, fc1_b,
                                                (const unsigned char*)maskp,
                                                (const int*)maskp, flag, wm);

    attn_mfma<<<B_ * G_, 256, 0, stream>>>(qb16, kb16, fkT16, wm,
                                           feat, conv_b, (float*)d_out);
}

// Round 8
// 95.776 us; speedup vs baseline: 6.2638x; 1.0842x over previous
//
#include <hip/hip_runtime.h>
#include <math.h>

#define B_  32
#define N_  100
#define G_  32
#define D_  1024
#define DG_ 32
#define FD_ 64

typedef __attribute__((ext_vector_type(8))) short short8;
typedef __attribute__((ext_vector_type(8))) unsigned short ushort8;
typedef __attribute__((ext_vector_type(4))) unsigned short ushort4v;
typedef __attribute__((ext_vector_type(4))) float f32x4;

__device__ inline unsigned short f2bf(float f) {
    unsigned int x = __float_as_uint(f);
    unsigned int r = (x + 0x7fffu + ((x >> 16) & 1u)) >> 16;  // RNE
    return (unsigned short)r;
}
__device__ inline unsigned short f2h(float f) {
    _Float16 h = (_Float16)f;
    return __builtin_bit_cast(unsigned short, h);
}
__device__ inline float h2f(unsigned short u) {
    return (float)__builtin_bit_cast(_Float16, u);
}
__device__ inline void load_lds16(const void* g, void* l) {
    __builtin_amdgcn_global_load_lds(
        (const __attribute__((address_space(1))) void*)g,
        (__attribute__((address_space(3))) void*)l, 16, 0, 0);
}

// ---------------------------------------------------------------------------
// Fused prep: [0,256) mask detect (1/8 scan) | [256,272) bbox prep |
// [272,1872) feat cast | [1872,2384) q_w | [2384,2896) k_w | [2896,3408) conv_w.
// ---------------------------------------------------------------------------
__global__ __launch_bounds__(256) void prep_kernel(
    const unsigned int* __restrict__ mask, int* __restrict__ flag,
    const float* __restrict__ bbox, float* __restrict__ prep,
    const float* __restrict__ feat, unsigned short* __restrict__ featb,
    const float* __restrict__ qw, unsigned short* __restrict__ wqb,
    const float* __restrict__ kw, unsigned short* __restrict__ wkb,
    const float* __restrict__ cw, unsigned short* __restrict__ wcb)
{
    const int bid = blockIdx.x;
    const int t = threadIdx.x;
    if (bid < 256) {
        const int nwords = (B_ * N_ * G_ * N_) / 4 / 8;   // 1/8 scan
        int v = 0;
        for (int i = bid * 256 + t; i < nwords; i += 256 * 256)
            v |= (mask[i] > 1u) ? 1 : 0;
        if (__any(v) && (t & 63) == 0) atomicOr(flag, 1);
        return;
    }
    if (bid < 272) {
        const int i = (bid - 256) * 256 + t;
        if (i < B_ * N_) {
            const float4 bb = *reinterpret_cast<const float4*>(bbox + (size_t)i * 4);
            const float bw = bb.z - bb.x + 1.0f, bh = bb.w - bb.y + 1.0f;
            float4 o0, o1;
            o0.x = 0.5f * (bb.x + bb.z);
            o0.y = 0.5f * (bb.y + bb.w);
            o0.z = __logf(bw);
            o0.w = __logf(bh);
            o1.x = 1.0f / bw;
            o1.y = 1.0f / bh;
            o1.z = 0.0f; o1.w = 0.0f;
            *reinterpret_cast<float4*>(prep + (size_t)i * 8)     = o0;
            *reinterpret_cast<float4*>(prep + (size_t)i * 8 + 4) = o1;
        }
        return;
    }
    const float* src;
    unsigned short* dst;
    int i;
    if (bid < 1872)      { src = feat; dst = featb; i = (bid - 272) * 256 + t; }
    else if (bid < 2384) { src = qw;   dst = wqb;   i = (bid - 1872) * 256 + t; }
    else if (bid < 2896) { src = kw;   dst = wkb;   i = (bid - 2384) * 256 + t; }
    else                 { src = cw;   dst = wcb;   i = (bid - 2896) * 256 + t; }
    const float4 a = reinterpret_cast<const float4*>(src)[i * 2 + 0];
    const float4 b = reinterpret_cast<const float4*>(src)[i * 2 + 1];
    ushort8 o;
    o[0] = f2bf(a.x); o[1] = f2bf(a.y); o[2] = f2bf(a.z); o[3] = f2bf(a.w);
    o[4] = f2bf(b.x); o[5] = f2bf(b.y); o[6] = f2bf(b.z); o[7] = f2bf(b.w);
    *reinterpret_cast<ushort8*>(&dst[i * 8]) = o;
}

// ---------------------------------------------------------------------------
// bf16 MFMA GEMM NT, 128x64 tile, BK=64, double-buffered LDS (T3 2-phase).
// z=0: q(+q_b). z=1: k(+k_b). z=2: fk (no bias). All outputs bf16.
// ---------------------------------------------------------------------------
__global__ __launch_bounds__(256) void mfma_gemm_nt(
    const unsigned short* __restrict__ A,
    const unsigned short* __restrict__ Wq,
    const unsigned short* __restrict__ Wk,
    const unsigned short* __restrict__ Wc,
    const float* __restrict__ bq, const float* __restrict__ bk,
    unsigned short* __restrict__ Q16, unsigned short* __restrict__ K16,
    unsigned short* __restrict__ F16)
{
    __shared__ short As0[128 * 64], As1[128 * 64];   // 16 KB each
    __shared__ short Bs0[64 * 64],  Bs1[64 * 64];    // 8 KB each

    const int z = blockIdx.z;
    const unsigned short* W = (z == 0) ? Wq : (z == 1) ? Wk : Wc;
    const float* bias        = (z == 0) ? bq : (z == 1) ? bk : nullptr;
    unsigned short* O        = (z == 0) ? Q16 : (z == 1) ? K16 : F16;

    const int m0 = blockIdx.x * 128;
    const int n0 = blockIdx.y * 64;
    const int t = threadIdx.x;
    const int lane = t & 63;
    const int wid = t >> 6;
    const int wr = wid >> 1, wc = wid & 1;
    const int lo = lane & 15, hi = lane >> 4;

    f32x4 acc[4][2] = {};

    auto STAGE = [&](short* dA, short* dB, int k0) {
#pragma unroll
        for (int c = 0; c < 4; ++c) {
            const int idx16 = c * 256 + t;
            const int row = idx16 >> 3;
            const int colb = ((idx16 & 7) * 16) ^ ((row & 7) << 4);
            load_lds16((const char*)(A + (size_t)(m0 + row) * D_ + k0) + colb,
                       (char*)dA + (c * 256 + wid * 64) * 16);
        }
#pragma unroll
        for (int c = 0; c < 2; ++c) {
            const int idx16 = c * 256 + t;
            const int row = idx16 >> 3;
            const int colb = ((idx16 & 7) * 16) ^ ((row & 7) << 4);
            load_lds16((const char*)(W + (size_t)(n0 + row) * D_ + k0) + colb,
                       (char*)dB + (c * 256 + wid * 64) * 16);
        }
    };

    auto COMPUTE = [&](const short* sA, const short* sB) {
#pragma unroll
        for (int ks = 0; ks < 2; ++ks) {
            short8 afr[4], bfr[2];
            const int kb = ks * 64 + hi * 16;
#pragma unroll
            for (int f = 0; f < 4; ++f) {
                const int am = wr * 64 + f * 16 + lo;
                afr[f] = *reinterpret_cast<const short8*>(
                    (const char*)sA + am * 128 + (kb ^ ((am & 7) << 4)));
            }
#pragma unroll
            for (int j = 0; j < 2; ++j) {
                const int bn = wc * 32 + j * 16 + lo;
                bfr[j] = *reinterpret_cast<const short8*>(
                    (const char*)sB + bn * 128 + (kb ^ ((bn & 7) << 4)));
            }
#pragma unroll
            for (int i = 0; i < 4; ++i)
#pragma unroll
                for (int j = 0; j < 2; ++j)
                    acc[i][j] = __builtin_amdgcn_mfma_f32_16x16x32_bf16(
                        afr[i], bfr[j], acc[i][j], 0, 0, 0);
        }
    };

    STAGE(As0, Bs0, 0);
    __syncthreads();
    for (int it = 0; it < 16; it += 2) {
        STAGE(As1, Bs1, (it + 1) << 6);
        COMPUTE(As0, Bs0);
        __syncthreads();
        if (it + 2 < 16) STAGE(As0, Bs0, (it + 2) << 6);
        COMPUTE(As1, Bs1);
        __syncthreads();
    }

#pragma unroll
    for (int j = 0; j < 2; ++j) {
        const int col = n0 + wc * 32 + j * 16 + lo;
        const float bv = bias ? bias[col] : 0.0f;
#pragma unroll
        for (int i = 0; i < 4; ++i) {
            const int mbase = m0 + wr * 64 + i * 16 + hi * 4;
#pragma unroll
            for (int r = 0; r < 4; ++r)
                O[(size_t)(mbase + r) * D_ + col] = f2bf(acc[i][j][r] + bv);
        }
    }
}

// ---------------------------------------------------------------------------
// pos_fc1: pairwise pos (hoisted, division-free) + f16 emb + fc1 MFMA +
// relu/log + mask fusion -> wm[b][q][g][128] f16 (granule-swizzled ^(q&7)).
// One block per (b,q), 4 waves. Writes 8KB contiguous per block.
// ---------------------------------------------------------------------------
__global__ __launch_bounds__(256) void pos_fc1_kernel(
    const float* __restrict__ prep, const float* __restrict__ fc1_w,
    const float* __restrict__ fc1_b,
    const unsigned char* __restrict__ mask8, const int* __restrict__ mask32,
    const int* __restrict__ flag, unsigned short* __restrict__ wm)
{
    __shared__ unsigned short embh[112 * 72];
    __shared__ unsigned short w1h[G_ * 72];
    __shared__ float b1[G_];
    __shared__ float tbl[8];
    __shared__ float pos4[N_][4];

    const int b = blockIdx.x / N_;
    const int q = blockIdx.x % N_;
    const int t = threadIdx.x;
    const int lane = t & 63;
    const int w = t >> 6;
    const int lo = lane & 15, hi = lane >> 4;

    const float4 pq0 = *reinterpret_cast<const float4*>(prep + (size_t)(b * N_ + q) * 8);
    const float4 pq1 = *reinterpret_cast<const float4*>(prep + (size_t)(b * N_ + q) * 8 + 4);
    const float cxq = pq0.x, cyq = pq0.y, lbwq = pq0.z, lbhq = pq0.w;
    const float rbwq = pq1.x, rbhq = pq1.y;

    for (int i = t; i < G_ * FD_; i += 256)
        w1h[(i >> 6) * 72 + (i & 63)] = f2h(fc1_w[i]);
    if (t < G_) b1[t] = fc1_b[t];
    if (t < 8)  tbl[t] = 100.0f / powf(1000.0f, (float)t * 0.125f);
    for (int i = t; i < 12 * 64; i += 256)
        embh[(100 + (i >> 6)) * 72 + (i & 63)] = 0;

    if (t < N_) {
        const float4 p0 = *reinterpret_cast<const float4*>(prep + (size_t)(b * N_ + t) * 8);
        pos4[t][0] = __logf(fmaxf(fabsf(cxq - p0.x) * rbwq, 1e-3f));
        pos4[t][1] = __logf(fmaxf(fabsf(cyq - p0.y) * rbhq, 1e-3f));
        pos4[t][2] = lbwq - p0.z;
        pos4[t][3] = lbhq - p0.w;
    }
    __syncthreads();

    for (int idx = t; idx < N_ * 32; idx += 256) {
        const int k = idx >> 5;
        const int p = (idx >> 3) & 3;
        const int j = idx & 7;
        const float dv = pos4[k][p] * tbl[j];
        embh[k * 72 + p * 16 + j]     = f2h(__sinf(dv));
        embh[k * 72 + p * 16 + 8 + j] = f2h(__cosf(dv));
    }
    __syncthreads();

    const bool bytemask = (*flag != 0);
    const int xq = q & 7;
    for (int tid = w; tid < 14; tid += 4) {
        const int mt = tid >> 1, nt = tid & 1;
        f32x4 d = {};
#pragma unroll
        for (int ks = 0; ks < 2; ++ks) {
            const short8 af = *reinterpret_cast<const short8*>(
                embh + (mt * 16 + lo) * 72 + ks * 32 + hi * 8);
            const short8 bf = *reinterpret_cast<const short8*>(
                w1h + (nt * 16 + lo) * 72 + ks * 32 + hi * 8);
            d = __builtin_amdgcn_mfma_f32_16x16x32_f16(af, bf, d, 0, 0, 0);
        }
        const int g = nt * 16 + lo;
        const int k0 = mt * 16 + hi * 4;
        const float bb = b1[g];
        unsigned int mby = 0;
        uint4 mi = {};
        if (k0 < N_) {
            const size_t midx = ((size_t)(b * N_ + q) * G_ + g) * N_ + k0;
            if (bytemask) mby = *(const unsigned int*)(mask8 + midx);
            else          mi  = *(const uint4*)(mask32 + midx);
        }
        ushort4v ov;
#pragma unroll
        for (int r = 0; r < 4; ++r) {
            const int k = k0 + r;
            const bool msk = bytemask
                ? (((mby >> (8 * r)) & 0xffu) != 0u)
                : ((r == 0 ? mi.x : r == 1 ? mi.y : r == 2 ? mi.z : mi.w) != 0u);
            const float aff = d[r] + bb;
            const float lv = __logf(fmaxf(fmaxf(aff, 0.0f), 1e-6f));
            ov[r] = f2h((k >= N_ || msk) ? -65504.0f : lv);
        }
        const size_t row = (size_t)(b * N_ + q) * G_ + g;   // [b][q][g]
        char* dst = (char*)wm + row * 256 + ((2 * k0) ^ (xq << 4));
        *reinterpret_cast<ushort4v*>(dst) = ov;
    }
}

// ---------------------------------------------------------------------------
// MFMA attention: one block per (b,g), 4 waves, one barrier.
// Stages wm (strided granules), transposes fk16 -> FL in-kernel (swizzled),
// QK^T -> in-reg softmax -> P in PW in-place -> PV -> epilogue.
// ---------------------------------------------------------------------------
__global__ __launch_bounds__(256) void attn_mfma(
    const unsigned short* __restrict__ qb, const unsigned short* __restrict__ kb,
    const unsigned short* __restrict__ fk16, const unsigned short* __restrict__ wm,
    const float* __restrict__ feat, const float* __restrict__ conv_b,
    float* __restrict__ out)
{
    __shared__ unsigned short PW[128 * 128];   // 32KB
    __shared__ unsigned short FL[DG_ * 128];   // 8KB

    const int bg = blockIdx.x;
    const int b = bg >> 5, g = bg & 31;
    const int t = threadIdx.x;
    const int lane = t & 63;
    const int w = t >> 6;
    const int lo = lane & 15, hi = lane >> 4;
    const float scale = 0.17677669529663687f;  // 1/sqrt(32)

    // ---- stage wm rows (q-strided granules) ----
    {
        const char* wbase = (const char*)wm + ((size_t)b * N_ * G_ + g) * 256;
        for (int u = t; u < 1600; u += 256) {
            const int qq = u >> 4, seg = u & 15;
            load_lds16(wbase + (size_t)qq * (G_ * 256) + seg * 16,
                       (char*)PW + u * 16);
        }
    }
    // ---- FL pad zero (n in [100,128)) ----
    for (int u = t; u < DG_ * 28; u += 256) {
        const int dg = u / 28, n = 100 + u % 28;
        *(unsigned short*)((char*)FL + dg * 256 +
                           (((n >> 3) ^ (dg & 7)) << 4) + (n & 7) * 2) = 0;
    }
    // ---- FL transpose from fk16 (dg rows, swizzled granules) ----
    for (int u = t; u < 400; u += 256) {
        const int n = u >> 2, c4 = u & 3;
        const ushort8 v = *reinterpret_cast<const ushort8*>(
            fk16 + (size_t)(b * N_ + n) * D_ + g * DG_ + c4 * 8);
#pragma unroll
        for (int j = 0; j < 8; ++j) {
            const int dg = c4 * 8 + j;
            *(unsigned short*)((char*)FL + dg * 256 +
                               (((n >> 3) ^ j) << 4) + (n & 7) * 2) = v[j];
        }
    }

    // ---- Q/K fragments direct from global bf16 ----
    short8 qf[2], kf[7];
#pragma unroll
    for (int mtl = 0; mtl < 2; ++mtl) {
        const int row = w * 32 + mtl * 16 + lo;
        const int rc = row < N_ ? row : N_ - 1;
        qf[mtl] = *reinterpret_cast<const short8*>(
            qb + (size_t)(b * N_ + rc) * D_ + g * DG_ + hi * 8);
    }
#pragma unroll
    for (int ct = 0; ct < 7; ++ct) {
        const int kr = ct * 16 + lo;
        const int krc = kr < N_ ? kr : N_ - 1;
        kf[ct] = *reinterpret_cast<const short8*>(
            kb + (size_t)(b * N_ + krc) * D_ + g * DG_ + hi * 8);
    }

    __syncthreads();   // wm staged + FL built

    f32x4 s[2][7];
#pragma unroll
    for (int mtl = 0; mtl < 2; ++mtl)
#pragma unroll
        for (int ct = 0; ct < 7; ++ct) {
            f32x4 z = {};
            s[mtl][ct] = __builtin_amdgcn_mfma_f32_16x16x32_bf16(
                qf[mtl], kf[ct], z, 0, 0, 0);
        }

#pragma unroll
    for (int mtl = 0; mtl < 2; ++mtl) {
        const int qr0 = w * 32 + mtl * 16 + hi * 4;
#pragma unroll
        for (int ct = 0; ct < 7; ++ct) {
            const int k = ct * 16 + lo;
#pragma unroll
            for (int r = 0; r < 4; ++r) {
                const int row = qr0 + r;
                const float wv = h2f(*(const unsigned short*)(
                    (const char*)PW + row * 256 + ((2 * k) ^ ((row & 7) << 4))));
                s[mtl][ct][r] = s[mtl][ct][r] * scale + wv;
            }
        }
    }

    float sm[2][4];
#pragma unroll
    for (int mtl = 0; mtl < 2; ++mtl) {
        f32x4 mv = s[mtl][0];
#pragma unroll
        for (int ct = 1; ct < 7; ++ct)
#pragma unroll
            for (int r = 0; r < 4; ++r) mv[r] = fmaxf(mv[r], s[mtl][ct][r]);
        float mx[4];
#pragma unroll
        for (int r = 0; r < 4; ++r) {
            float m = mv[r];
            m = fmaxf(m, __shfl_xor(m, 1));
            m = fmaxf(m, __shfl_xor(m, 2));
            m = fmaxf(m, __shfl_xor(m, 4));
            m = fmaxf(m, __shfl_xor(m, 8));
            mx[r] = m;
        }
        f32x4 sv = {};
#pragma unroll
        for (int ct = 0; ct < 7; ++ct)
#pragma unroll
            for (int r = 0; r < 4; ++r) {
                const float e = __expf(s[mtl][ct][r] - mx[r]);
                s[mtl][ct][r] = e;
                sv[r] += e;
            }
#pragma unroll
        for (int r = 0; r < 4; ++r) {
            float ss = sv[r];
            ss += __shfl_xor(ss, 1);
            ss += __shfl_xor(ss, 2);
            ss += __shfl_xor(ss, 4);
            ss += __shfl_xor(ss, 8);
            sm[mtl][r] = 1.0f / ss;
        }
    }

#pragma unroll
    for (int mtl = 0; mtl < 2; ++mtl) {
        const int qr0 = w * 32 + mtl * 16 + hi * 4;
#pragma unroll
        for (int ct = 0; ct < 7; ++ct) {
            const int col = ct * 16 + lo;
#pragma unroll
            for (int r = 0; r < 4; ++r) {
                const int row = qr0 + r;
                *(unsigned short*)((char*)PW + row * 256 +
                                   ((2 * col) ^ ((row & 7) << 4))) =
                    f2bf(s[mtl][ct][r] * sm[mtl][r]);
            }
        }
    }
    {
        const int zr = w * 32 + (lane & 31);
        const int zg = 14 + (lane >> 5);
        short8 zs = {};
        *reinterpret_cast<short8*>(
            (char*)PW + zr * 256 + ((zg * 16) ^ ((zr & 7) << 4))) = zs;
    }

    f32x4 o[2][2] = {};
#pragma unroll
    for (int ks = 0; ks < 4; ++ks) {
        short8 pa[2], fb[2];
#pragma unroll
        for (int mtl = 0; mtl < 2; ++mtl) {
            const int prow = w * 32 + mtl * 16 + lo;
            pa[mtl] = *reinterpret_cast<const short8*>(
                (const char*)PW + prow * 256 +
                ((ks * 64 + hi * 16) ^ ((prow & 7) << 4)));
        }
#pragma unroll
        for (int nt = 0; nt < 2; ++nt) {
            const int dg = nt * 16 + lo;
            fb[nt] = *reinterpret_cast<const short8*>(
                (const char*)FL + dg * 256 +
                ((ks * 64 + hi * 16) ^ ((dg & 7) << 4)));
        }
#pragma unroll
        for (int mtl = 0; mtl < 2; ++mtl)
#pragma unroll
            for (int nt = 0; nt < 2; ++nt)
                o[mtl][nt] = __builtin_amdgcn_mfma_f32_16x16x32_bf16(
                    pa[mtl], fb[nt], o[mtl][nt], 0, 0, 0);
    }

#pragma unroll
    for (int mtl = 0; mtl < 2; ++mtl) {
        const int qr0 = w * 32 + mtl * 16 + hi * 4;
#pragma unroll
        for (int nt = 0; nt < 2; ++nt) {
            const int col = g * DG_ + nt * 16 + lo;
            const float cb = conv_b[col];
#pragma unroll
            for (int r = 0; r < 4; ++r) {
                const int q = qr0 + r;
                if (q < N_) {
                    const size_t gi = (size_t)(b * N_ + q) * D_ + col;
                    out[gi] = fmaxf(feat[gi] + o[mtl][nt][r] + cb, 0.0f);
                }
            }
        }
    }
}

// ---------------------------------------------------------------------------
extern "C" void kernel_launch(void* const* d_in, const int* in_sizes, int n_in,
                              void* d_out, int out_size, void* d_ws, size_t ws_size,
                              hipStream_t stream)
{
    const float* feat   = (const float*)d_in[0];
    const float* bbox   = (const float*)d_in[1];
    const void*  maskp  = d_in[2];
    const float* fc1_w  = (const float*)d_in[3];
    const float* fc1_b  = (const float*)d_in[4];
    const float* q_w    = (const float*)d_in[5];
    const float* q_b    = (const float*)d_in[6];
    const float* k_w    = (const float*)d_in[7];
    const float* k_b    = (const float*)d_in[8];
    const float* conv_w = (const float*)d_in[9];
    const float* conv_b = (const float*)d_in[10];

    const int BN_D  = B_ * N_ * D_;          // 3,276,800
    const int DD    = D_ * D_;               // 1,048,576
    const int WM_N  = B_ * G_ * N_ * 128;    // 13,107,200

    unsigned short* ws16 = (unsigned short*)d_ws;
    unsigned short* qb16  = ws16;
    unsigned short* kb16  = qb16 + BN_D;
    unsigned short* fk16  = kb16 + BN_D;
    unsigned short* wm    = fk16 + BN_D;
    int* flag = (int*)(wm + WM_N);
    float* prep = (float*)(flag + 64);

    // bf16 cast staging aliases wm (dead before pos_fc1 writes wm)
    unsigned short* featb = wm;
    unsigned short* wqb   = featb + BN_D;
    unsigned short* wkb   = wqb + DD;
    unsigned short* wcb   = wkb + DD;

    hipMemsetAsync(flag, 0, sizeof(int), stream);
    prep_kernel<<<3408, 256, 0, stream>>>((const unsigned int*)maskp, flag,
                                          bbox, prep, feat, featb,
                                          q_w, wqb, k_w, wkb, conv_w, wcb);

    dim3 gg(B_ * N_ / 128, D_ / 64, 3);  // (25, 16, 3)
    mfma_gemm_nt<<<gg, 256, 0, stream>>>(featb, wqb, wkb, wcb, q_b, k_b,
                                         qb16, kb16, fk16);

    pos_fc1_kernel<<<B_ * N_, 256, 0, stream>>>(prep, fc1_w, fc1_b,
                                                (const unsigned char*)maskp,
                                                (const int*)maskp, flag, wm);

    attn_mfma<<<B_ * G_, 256, 0, stream>>>(qb16, kb16, fk16, wm,
                                           feat, conv_b, (float*)d_out);
}